// Round 12
// baseline (539.545 us; speedup 1.0000x reference)
//
#include <hip/hip_runtime.h>

#define N_ATOMS 100000
#define E_ATOMS 200000
#define N_AMINO 10240
#define E_AMINO 20480
#define NGRAPH 512
#define DIN0 40
#define D_E 11
#define HD 20
#define D_AA 8
#define HA 128
#define KS 3
#define TL 7
#define F1 256
#define F2 128
#define F3 64
#define NTILE 16  // nodes per edge-kernel tile (100000 % 16 == 0)
#define ECAP 64   // staged edges per chunk (mean 32/tile; loop handles overflow)
#define EAW 12    // eaP row (u16): 11 attrs + 1.0 pad; 24 B, u32-aligned

typedef unsigned short u16;
typedef unsigned int u32;
typedef __attribute__((ext_vector_type(8))) short short8;
typedef __attribute__((ext_vector_type(4))) float f32x4;

__device__ __forceinline__ float b2f(u16 u) {
    union { u32 i; float f; } v; v.i = ((u32)u) << 16; return v.f;
}
__device__ __forceinline__ u16 f2b(float f) {
    union { float f; u32 i; } v; v.f = f;
    u32 x = v.i;
    return (u16)((x + (((x >> 16) & 1u) + 0x7fffu)) >> 16);
}

// ---------------------------------------------------------------------------
// k_prep: merged prep + ARMA weight pack.
// Part A: Mb matrices in MFMA B-fragment order (bf16; 272 padded cols =
// W(220)|edge-bias(20)|root(20)|0(12), K padded to 32*KB) + aa feature cols
// + zero CSR counts.  Part B: ARMA weight pack (Wp).
#define MB1_ELEMS 17408   // DIN=40 -> KB=2, 2*8704
#define MB2_ELEMS 8704    // DIN=20 -> KB=1
#define PREP0_N (MB1_ELEMS + 2 * MB2_ELEMS + N_AMINO * D_AA + 2 * N_ATOMS + 2 * N_AMINO)
#define WP0_ELEMS (KS * 8192)
#define WP1_ELEMS (6 * KS * 20480)
#define PREP_N (PREP0_N + WP0_ELEMS + WP1_ELEMS)
__global__ __launch_bounds__(256) void k_prep(
    const float* __restrict__ w1, const float* __restrict__ nb1, const float* __restrict__ r1,
    const float* __restrict__ w2, const float* __restrict__ nb2, const float* __restrict__ r2,
    const float* __restrict__ w3, const float* __restrict__ nb3, const float* __restrict__ r3,
    u16* __restrict__ Mb1, u16* __restrict__ Mb2, u16* __restrict__ Mb3,
    const float* __restrict__ af, float* __restrict__ aa,
    int* __restrict__ cs, int* __restrict__ cd,
    int* __restrict__ ca, int* __restrict__ cl,
    const float* __restrict__ ai, const float* __restrict__ aw,
    const float* __restrict__ arw, u16* __restrict__ Wp) {
    int t = blockIdx.x * 256 + threadIdx.x;
    if (t < MB1_ELEMS) {
        int kb = t / 8704, rem = t % 8704;
        int c = rem >> 5, qj = rem & 31;
        int krow = kb * 32 + qj;
        float v = 0.f;
        if (krow < DIN0) {
            if (c < 220)      v = w1[(c / 20) * 800 + krow * 20 + (c % 20)];
            else if (c < 240) v = nb1[krow * 20 + (c - 220)];
            else if (c < 260) v = r1[krow * 20 + (c - 240)];
        }
        Mb1[t] = f2b(v);
    } else if (t < MB1_ELEMS + MB2_ELEMS) {
        int tt = t - MB1_ELEMS;
        int c = tt >> 5, qj = tt & 31;
        float v = 0.f;
        if (qj < HD) {
            if (c < 220)      v = w2[(c / 20) * 400 + qj * 20 + (c % 20)];
            else if (c < 240) v = nb2[qj * 20 + (c - 220)];
            else if (c < 260) v = r2[qj * 20 + (c - 240)];
        }
        Mb2[tt] = f2b(v);
    } else if (t < MB1_ELEMS + 2 * MB2_ELEMS) {
        int tt = t - MB1_ELEMS - MB2_ELEMS;
        int c = tt >> 5, qj = tt & 31;
        float v = 0.f;
        if (qj < HD) {
            if (c < 220)      v = w3[(c / 20) * 400 + qj * 20 + (c % 20)];
            else if (c < 240) v = nb3[qj * 20 + (c - 220)];
            else if (c < 260) v = r3[qj * 20 + (c - 240)];
        }
        Mb3[tt] = f2b(v);
    } else if (t < MB1_ELEMS + 2 * MB2_ELEMS + N_AMINO * D_AA) {
        int idx = t - MB1_ELEMS - 2 * MB2_ELEMS, m = idx / D_AA, j = idx % D_AA;
        aa[m * 28 + HD + j] = af[idx];
    } else if (t < PREP0_N) {
        int z = t - MB1_ELEMS - 2 * MB2_ELEMS - N_AMINO * D_AA;
        if (z < N_ATOMS) cs[z] = 0;
        else if (z < 2 * N_ATOMS) cd[z - N_ATOMS] = 0;
        else if (z < 2 * N_ATOMS + N_AMINO) ca[z - 2 * N_ATOMS] = 0;
        else if (z < 2 * N_ATOMS + 2 * N_AMINO) cl[z - 2 * N_ATOMS - N_AMINO] = 0;
    } else {
        int g = t - PREP0_N;
        if (g < WP0_ELEMS) {
            int k = g / 8192, r = g % 8192;
            int kb = r >> 12, rem = r & 4095;
            int c = rem >> 5, qj = rem & 31;
            int krow = kb * 32 + qj;
            float v = 0.f;
            if (krow < 28)      v = ai[((size_t)k * 28 + krow) * HA + c];
            else if (krow < 56) v = arw[((size_t)k * 28 + (krow - 28)) * HA + c];
            Wp[g] = f2b(v);
        } else if (g < WP0_ELEMS + WP1_ELEMS) {
            int gg = g - WP0_ELEMS;
            int mat = gg / 20480, r = gg % 20480;
            int kb = r / 4096, rem = r & 4095;
            int c = rem >> 5, qj = rem & 31;
            int krow = kb * 32 + qj;
            int tm1 = mat / KS, k = mat % KS;
            float v = 0.f;
            if (krow < 128)      v = aw[((size_t)mat * 128 + krow) * HA + c];
            else if (krow < 156) v = arw[(((size_t)(tm1 + 1) * KS + k) * 28 + (krow - 128)) * HA + c];
            Wp[g] = f2b(v);
        }
    }
}

// ---------------------------------------------------------------------------
#define NBS 98
#define NBA 10

__global__ __launch_bounds__(256) void k_csr_count(
    const int* __restrict__ esrc, const int* __restrict__ edst,
    const int* __restrict__ adst, const int* __restrict__ lbl,
    int* __restrict__ cs, int* __restrict__ cd,
    int* __restrict__ ca, int* __restrict__ cl) {
    int t = blockIdx.x * 256 + threadIdx.x;
    if (t < E_ATOMS) atomicAdd(cs + esrc[t], 1);
    else if (t < 2 * E_ATOMS) atomicAdd(cd + edst[t - E_ATOMS], 1);
    else if (t < 2 * E_ATOMS + E_AMINO) atomicAdd(ca + adst[t - 2 * E_ATOMS], 1);
    else if (t < 2 * E_ATOMS + E_AMINO + N_ATOMS) atomicAdd(cl + lbl[t - 2 * E_ATOMS - E_AMINO], 1);
}
__device__ __forceinline__ void seg_decode(int bx, int* blk, int* n, int* which) {
    if (bx < NBS)            { *which = 0; *blk = bx;             *n = N_ATOMS; }
    else if (bx < 2 * NBS)   { *which = 1; *blk = bx - NBS;       *n = N_ATOMS; }
    else if (bx < 2 * NBS + NBA) { *which = 2; *blk = bx - 2 * NBS; *n = N_AMINO; }
    else                     { *which = 3; *blk = bx - 2 * NBS - NBA; *n = N_AMINO; }
}
__global__ __launch_bounds__(256) void k_scan1(
    const int* __restrict__ cs, int* __restrict__ soff,
    const int* __restrict__ cd, int* __restrict__ doff,
    const int* __restrict__ ca, int* __restrict__ aoff,
    const int* __restrict__ cl, int* __restrict__ loff,
    int* __restrict__ bsum) {
    int blk, n, which;
    seg_decode(blockIdx.x, &blk, &n, &which);
    const int* c = which == 0 ? cs : which == 1 ? cd : which == 2 ? ca : cl;
    int* o = which == 0 ? soff : which == 1 ? doff : which == 2 ? aoff : loff;
    int tx = threadIdx.x, lane = tx & 63, w = tx >> 6;
    int i0 = blk * 1024 + tx * 4;
    int v[4];
#pragma unroll
    for (int q = 0; q < 4; ++q) v[q] = (i0 + q < n) ? c[i0 + q] : 0;
    int s = v[0] + v[1] + v[2] + v[3];
    int inc = s;
#pragma unroll
    for (int d = 1; d < 64; d <<= 1) {
        int u = __shfl_up(inc, d, 64);
        if (lane >= d) inc += u;
    }
    __shared__ int wsum[4];
    if (lane == 63) wsum[w] = inc;
    __syncthreads();
    int wo = 0;
    for (int i = 0; i < w; ++i) wo += wsum[i];
    int run = wo + inc - s;
#pragma unroll
    for (int q = 0; q < 4; ++q) {
        if (i0 + q < n) o[i0 + q] = run;
        run += v[q];
    }
    if (tx == 255) bsum[blockIdx.x] = wo + inc;
}
__global__ __launch_bounds__(128) void k_scan2(
    int* __restrict__ bsum, int* __restrict__ soff, int* __restrict__ doff,
    int* __restrict__ aoff, int* __restrict__ loff) {
    int bx = blockIdx.x;
    int nb   = (bx < 2) ? NBS : NBA;
    int base = (bx == 0) ? 0 : (bx == 1) ? NBS : (bx == 2) ? 2 * NBS : 2 * NBS + NBA;
    int* b = bsum + base;
    int tx = threadIdx.x, lane = tx & 63;
    int v = (tx < nb) ? b[tx] : 0;
    int inc = v;
#pragma unroll
    for (int d = 1; d < 64; d <<= 1) {
        int u = __shfl_up(inc, d, 64);
        if (lane >= d) inc += u;
    }
    __shared__ int w0;
    if (tx == 63) w0 = inc;
    __syncthreads();
    int excl = inc - v + ((tx >= 64) ? w0 : 0);
    if (tx < nb) b[tx] = excl;
    if (tx == nb - 1) {
        int tot = excl + v;
        if (bx == 0) soff[N_ATOMS] = tot;
        else if (bx == 1) doff[N_ATOMS] = tot;
        else if (bx == 2) aoff[N_AMINO] = tot;
        else loff[N_AMINO] = tot;
    }
}
__global__ __launch_bounds__(256) void k_scan3(
    int* __restrict__ soff, int* __restrict__ doff,
    int* __restrict__ aoff, int* __restrict__ loff,
    const int* __restrict__ bsum,
    int* __restrict__ us, int* __restrict__ ud,
    int* __restrict__ ua, int* __restrict__ ul) {
    int blk, n, which;
    seg_decode(blockIdx.x, &blk, &n, &which);
    int* o = which == 0 ? soff : which == 1 ? doff : which == 2 ? aoff : loff;
    int* cu = which == 0 ? us : which == 1 ? ud : which == 2 ? ua : ul;
    int add = bsum[blockIdx.x];
    int i0 = blk * 1024 + threadIdx.x * 4;
#pragma unroll
    for (int q = 0; q < 4; ++q)
        if (i0 + q < n) { int val = o[i0 + q] + add; o[i0 + q] = val; cu[i0 + q] = val; }
}
// fill: src slots -> srcP/eaP(bf16 x11 + 1.0 pad) + sdp (src-slot -> dst-pos),
// amino eids+nrm, label->node
__global__ __launch_bounds__(256) void k_csr_fill(
    const int* __restrict__ esrc, const int* __restrict__ edst,
    const float* __restrict__ ea,
    int* __restrict__ us, int* __restrict__ srcP, u16* __restrict__ eaP,
    int* __restrict__ ud, int* __restrict__ sdp,
    const int* __restrict__ aei, int* __restrict__ ua, int* __restrict__ aeid,
    const int* __restrict__ aoff, float* __restrict__ nrm,
    const int* __restrict__ lbl, int* __restrict__ ul, int* __restrict__ lnid) {
    int t = blockIdx.x * 256 + threadIdx.x;
    if (t < E_ATOMS) {
        int jj = atomicAdd(us + esrc[t], 1);
        srcP[jj] = esrc[t];
        const float* e0 = ea + (size_t)t * D_E;
        u16* e1 = eaP + (size_t)jj * EAW;
#pragma unroll
        for (int k = 0; k < D_E; ++k) e1[k] = f2b(e0[k]);
        e1[D_E] = f2b(1.0f);   // pad = 1.0: folds edge-MLP bias into the 12-dot
        sdp[jj] = atomicAdd(ud + edst[t], 1);   // dst-CSR position for this edge
    } else if (t < E_ATOMS + E_AMINO) {
        int e = t - E_ATOMS;
        int p = atomicAdd(ua + aei[E_AMINO + e], 1);
        aeid[p] = e;
    } else if (t < E_ATOMS + 2 * E_AMINO) {
        int e = t - E_ATOMS - E_AMINO;
        int s = aei[e], d = aei[E_AMINO + e];
        int ds = aoff[s + 1] - aoff[s], dd = aoff[d + 1] - aoff[d];
        float a = ds > 0 ? rsqrtf((float)ds) : 0.f;
        float b = dd > 0 ? rsqrtf((float)dd) : 0.f;
        nrm[e] = a * b;
    } else if (t < E_ATOMS + 2 * E_AMINO + N_ATOMS) {
        int n = t - E_ATOMS - 2 * E_AMINO;
        int p = atomicAdd(ul + lbl[n], 1);
        lnid[p] = n;
    }
}

// ---------------------------------------------------------------------------
// NNConv edge v13 (= v11 structure + 2-output phase 2): MFMA phase-1 over 17
// col-tiles (240 msg-dot cols -> packed y3; 20 root cols -> selfm = x@root +
// bias). Phase 2: 2 outputs per lane, packed u32 store, dst-ordered msg.
// h recompute is NOT fused (R11 lesson: scattered gather on the staging
// critical path serializes the block and amplifies HBM traffic).
template <int DIN, int KB, bool RAW>
__global__ __launch_bounds__(256, 6) void nnconv_edge13(
    const void* __restrict__ xin, const u16* __restrict__ eaP,
    const int* __restrict__ srcP, const int* __restrict__ sdp,
    const int* __restrict__ soff, const u16* __restrict__ Mb,
    const float* __restrict__ bnn, u16* __restrict__ msg,
    u16* __restrict__ selfm) {
    constexpr int KPAD = KB * 32;
    __shared__ __align__(16) float y3[NTILE * 240];
    __shared__ __align__(16) u16 As[NTILE * KPAD];
    __shared__ __align__(16) float eaS[ECAP * 12];
    __shared__ int srcS[ECAP];
    __shared__ int sdpS[ECAP];
    int tx = threadIdx.x;
    int n0 = blockIdx.x * NTILE;         // N_ATOMS % NTILE == 0
    int j0 = soff[n0], j1 = soff[n0 + NTILE];
    // stage X as bf16 A-fragments (node-major rows, zero-pad k >= DIN)
    for (int i = tx; i < NTILE * KPAD; i += 256) {
        int node = i / KPAD, k = i % KPAD;
        u16 v = 0;
        if (k < DIN)
            v = RAW ? f2b(((const float*)xin)[(size_t)(n0 + node) * DIN + k])
                    : ((const u16*)xin)[(size_t)(n0 + node) * DIN + k];
        As[i] = v;
    }
    // stage phase-2 chunk 0
    {
        int cn0 = j1 - j0; if (cn0 > ECAP) cn0 = ECAP;
        for (int i = tx; i < cn0; i += 256) {
            srcS[i] = srcP[j0 + i] - n0;
            sdpS[i] = sdp[j0 + i];
        }
        const u32* eg = (const u32*)(eaP + (size_t)j0 * EAW);
        for (int i = tx; i < cn0 * 6; i += 256) {
            u32 pv = eg[i];
            eaS[2 * i]     = b2f((u16)(pv & 0xffff));
            eaS[2 * i + 1] = b2f((u16)(pv >> 16));
        }
    }
    __syncthreads();
    // phase 1: MFMA over 17 col-tiles; wave handles ct = wave, wave+4, ...
    {
        int wave = tx >> 6, lane = tx & 63;
        int m = lane & 15, q = lane >> 4;
        short8 aF[KB];
#pragma unroll
        for (int kb = 0; kb < KB; ++kb)
            aF[kb] = *(const short8*)&As[m * KPAD + kb * 32 + q * 8];
        for (int ct = wave; ct < 17; ct += 4) {
            int c0 = ct * 16;
            f32x4 acc = {0.f, 0.f, 0.f, 0.f};
#pragma unroll
            for (int kb = 0; kb < KB; ++kb) {
                short8 bF = *(const short8*)(Mb + (size_t)kb * 8704 + (size_t)(c0 + m) * 32 + q * 8);
                acc = __builtin_amdgcn_mfma_f32_16x16x32_bf16(aF[kb], bF, acc, 0, 0, 0);
            }
            int c = c0 + m;
            if (c < 240) {
                int slot = (c < 220) ? (c % 20) * 12 + c / 20 : (c - 220) * 12 + 11;
#pragma unroll
                for (int r = 0; r < 4; ++r)
                    y3[(q * 4 + r) * 240 + slot] = acc[r];
            } else if (c < 260) {
                float bv = bnn[c - 240];
#pragma unroll
                for (int r = 0; r < 4; ++r)
                    selfm[(size_t)(n0 + q * 4 + r) * HD + (c - 240)] = f2b(acc[r] + bv);
            }
        }
    }
    __syncthreads();
    // phase 2: task p = (edge e, half h -> outputs 2h, 2h+1); 12-dots;
    // packed u32 store in dst order.
    int c0 = j0;
    while (true) {
        int cn = j1 - c0; if (cn > ECAP) cn = ECAP;
        for (int p = tx; p < cn * 10; p += 256) {
            int e = p / 10, h = p - e * 10;
            const float4* ev = (const float4*)&eaS[e * 12];
            float4 e0 = ev[0], e1 = ev[1], e2 = ev[2];
            const float* yb = &y3[srcS[e] * 240];
            const float4* ya = (const float4*)(yb + (2 * h) * 12);
            const float4* yc = (const float4*)(yb + (2 * h + 1) * 12);
            float4 a0 = ya[0], a1 = ya[1], a2 = ya[2];
            float4 b0 = yc[0], b1 = yc[1], b2 = yc[2];
            float mv0 = e0.x * a0.x + e0.y * a0.y + e0.z * a0.z + e0.w * a0.w
                      + e1.x * a1.x + e1.y * a1.y + e1.z * a1.z + e1.w * a1.w
                      + e2.x * a2.x + e2.y * a2.y + e2.z * a2.z + e2.w * a2.w;
            float mv1 = e0.x * b0.x + e0.y * b0.y + e0.z * b0.z + e0.w * b0.w
                      + e1.x * b1.x + e1.y * b1.y + e1.z * b1.z + e1.w * b1.w
                      + e2.x * b2.x + e2.y * b2.y + e2.z * b2.z + e2.w * b2.w;
            u32 pk = (u32)f2b(mv0) | ((u32)f2b(mv1) << 16);
            *(u32*)(msg + (size_t)sdpS[e] * HD + 2 * h) = pk;
        }
        c0 += cn;
        if (c0 >= j1) break;
        // rare: tile had >ECAP edges — restage next chunk
        __syncthreads();
        int cm = j1 - c0; if (cm > ECAP) cm = ECAP;
        for (int i = tx; i < cm; i += 256) {
            srcS[i] = srcP[c0 + i] - n0;
            sdpS[i] = sdp[c0 + i];
        }
        const u32* eg = (const u32*)(eaP + (size_t)c0 * EAW);
        for (int i = tx; i < cm * 6; i += 256) {
            u32 pv = eg[i];
            eaS[2 * i]     = b2f((u16)(pv & 0xffff));
            eaS[2 * i + 1] = b2f((u16)(pv >> 16));
        }
        __syncthreads();
    }
}

// NNConv reduce v2: pure streaming. h = relu(selfm + sum of contiguous
// dst-ordered msg rows). No x, no root, no indirection.
__global__ __launch_bounds__(256) void nnconv_reduce2(
    const u16* __restrict__ selfm, const int* __restrict__ doff,
    const u16* __restrict__ msg, u16* __restrict__ hout) {
    int t = blockIdx.x * 256 + threadIdx.x;
    if (t >= N_ATOMS * HD) return;
    int n = t / HD, o = t - n * HD;
    float acc = b2f(selfm[t]);
    int j1 = doff[n + 1];
    for (int j = doff[n]; j < j1; ++j)
        acc += b2f(msg[(size_t)j * HD + o]);
    hout[t] = f2b(fmaxf(acc, 0.f));
}

// aa gather: label-CSR segmented sum of h3
__global__ __launch_bounds__(256) void aa_gather(
    const u16* __restrict__ h3, const int* __restrict__ loff,
    const int* __restrict__ lnid, float* __restrict__ aa) {
    int t = blockIdx.x * 256 + threadIdx.x;
    if (t >= N_AMINO * HD) return;
    int m = t / HD, o = t % HD;
    float s = 0.f;
    int j1 = loff[m + 1];
    for (int j = loff[m]; j < j1; ++j)
        s += b2f(h3[(size_t)lnid[j] * HD + o]);
    aa[m * 28 + o] = s;
}

// ---------------------------------------------------------------------------
// ARMA layer 0 fused: gather A0-tile = [gather(aa)(28)|aa(28)|0(8)] into LDS,
// then O_k = relu(A0 @ [init_k;root0_k] + bias_k) for all 3 stacks via MFMA.
__global__ __launch_bounds__(256) void arma_l0f(
    const float* __restrict__ aa, const int* __restrict__ aoff,
    const int* __restrict__ aeid, const int* __restrict__ aei,
    const float* __restrict__ nrm, const u16* __restrict__ Wp0,
    const float* __restrict__ abi, u16* __restrict__ O, size_t kstride) {
    __shared__ __align__(16) u16 As[64 * 64];
    int tx = threadIdx.x;
    int n0b = blockIdx.x * 64;
    for (int i = tx; i < 64 * 64; i += 256) {
        int nl = i >> 6, c = i & 63;
        int n = n0b + nl;
        float v = 0.f;
        if (c < 28) {
            int j1 = aoff[n + 1];
            for (int jj = aoff[n]; jj < j1; ++jj) {
                int e = aeid[jj], s = aei[e];
                v += nrm[e] * aa[(size_t)s * 28 + c];
            }
        } else if (c < 56) {
            v = aa[(size_t)n * 28 + (c - 28)];
        }
        As[i] = f2b(v);
    }
    __syncthreads();
    int wave = tx >> 6, lane = tx & 63;
    int m = lane & 15, q = lane >> 4;
    short8 aF[2];
#pragma unroll
    for (int kb = 0; kb < 2; ++kb)
        aF[kb] = *(const short8*)&As[(wave * 16 + m) * 64 + kb * 32 + q * 8];
    int n0 = n0b + wave * 16;
    for (int k = 0; k < KS; ++k) {
        const u16* W = Wp0 + (size_t)k * 8192;
        u16* Ok = O + (size_t)k * kstride;
        const float* bk = abi + (size_t)k * HA;   // abi[t=0][k][:]
#pragma unroll
        for (int ct = 0; ct < 8; ++ct) {
            int c0 = ct * 16;
            float b = bk[c0 + m];
            f32x4 acc = {b, b, b, b};
#pragma unroll
            for (int kb = 0; kb < 2; ++kb) {
                short8 bF = *(const short8*)(W + (size_t)((kb * 128 + c0 + m) * 32 + q * 8));
                acc = __builtin_amdgcn_mfma_f32_16x16x32_bf16(aF[kb], bF, acc, 0, 0, 0);
            }
#pragma unroll
            for (int r = 0; r < 4; ++r)
                Ok[(size_t)(n0 + q * 4 + r) * HA + c0 + m] = f2b(fmaxf(acc[r], 0.f));
        }
    }
}

// ARMA layer t>=1 fused: gather G=sum nrm*Oprev[src] into LDS (+aa cols),
// then O = relu([G|aa] @ [W;root] + bias) via MFMA (K=160). 64-node tiles.
__global__ __launch_bounds__(256) void arma_lt(
    const u16* __restrict__ Oprev, const u16* __restrict__ Wm,
    const float* __restrict__ abit, const float* __restrict__ aa,
    const int* __restrict__ aoff, const int* __restrict__ aeid,
    const int* __restrict__ aei, const float* __restrict__ nrm,
    u16* __restrict__ Onext, size_t kstride) {
    __shared__ __align__(16) u16 As[64 * 160];
    int tx = threadIdx.x;
    int k = blockIdx.y;
    int n0b = blockIdx.x * 64;
    const u16* Op = Oprev + (size_t)k * kstride;
    const u16* W  = Wm + (size_t)k * 20480;   // per-stack weight offset
    // gather phase: 1024 tasks = 64 nodes x 16 col-blocks (8 bf16 each)
    for (int i = tx; i < 1024; i += 256) {
        int nl = i >> 4, cb = i & 15;
        int n = n0b + nl;
        int j1 = aoff[n + 1];
        float a0 = 0.f, a1 = 0.f, a2 = 0.f, a3 = 0.f;
        float a4 = 0.f, a5 = 0.f, a6 = 0.f, a7 = 0.f;
        for (int jj = aoff[n]; jj < j1; ++jj) {
            int e = aeid[jj], s = aei[e];
            float nm = nrm[e];
            uint4 hv = *(const uint4*)(Op + (size_t)s * HA + cb * 8);
            a0 += nm * b2f((u16)(hv.x & 0xffff));
            a1 += nm * b2f((u16)(hv.x >> 16));
            a2 += nm * b2f((u16)(hv.y & 0xffff));
            a3 += nm * b2f((u16)(hv.y >> 16));
            a4 += nm * b2f((u16)(hv.z & 0xffff));
            a5 += nm * b2f((u16)(hv.z >> 16));
            a6 += nm * b2f((u16)(hv.w & 0xffff));
            a7 += nm * b2f((u16)(hv.w >> 16));
        }
        uint4 pk;
        pk.x = (u32)f2b(a0) | ((u32)f2b(a1) << 16);
        pk.y = (u32)f2b(a2) | ((u32)f2b(a3) << 16);
        pk.z = (u32)f2b(a4) | ((u32)f2b(a5) << 16);
        pk.w = (u32)f2b(a6) | ((u32)f2b(a7) << 16);
        *(uint4*)&As[nl * 160 + cb * 8] = pk;
    }
    // aa cols 128..159: 256 tasks = 64 nodes x 4 col-blocks
    {
        int nl = tx >> 2, cb = tx & 3;
        int n = n0b + nl;
        float av[8];
#pragma unroll
        for (int j = 0; j < 8; ++j) {
            int c = cb * 8 + j;
            av[j] = (c < 28) ? aa[(size_t)n * 28 + c] : 0.f;
        }
        uint4 pk;
        pk.x = (u32)f2b(av[0]) | ((u32)f2b(av[1]) << 16);
        pk.y = (u32)f2b(av[2]) | ((u32)f2b(av[3]) << 16);
        pk.z = (u32)f2b(av[4]) | ((u32)f2b(av[5]) << 16);
        pk.w = (u32)f2b(av[6]) | ((u32)f2b(av[7]) << 16);
        *(uint4*)&As[nl * 160 + 128 + cb * 8] = pk;
    }
    __syncthreads();
    // MFMA phase: wave w -> rows n0b + w*16 .. +16, K = 160 (5 kb-blocks)
    int wave = tx >> 6, lane = tx & 63;
    int m = lane & 15, q = lane >> 4;
    int wl = wave * 16 + m;
    short8 aF[5];
#pragma unroll
    for (int kb = 0; kb < 5; ++kb)
        aF[kb] = *(const short8*)&As[wl * 160 + kb * 32 + q * 8];
    int n0 = n0b + wave * 16;
    u16* On = Onext + (size_t)k * kstride;
    const float* bk = abit + (size_t)k * HA;
#pragma unroll
    for (int ct = 0; ct < 8; ++ct) {
        int c0 = ct * 16;
        float b = bk[c0 + m];
        f32x4 acc = {b, b, b, b};
#pragma unroll
        for (int kb = 0; kb < 5; ++kb) {
            short8 bF = *(const short8*)(W + (size_t)((kb * 128 + c0 + m) * 32 + q * 8));
            acc = __builtin_amdgcn_mfma_f32_16x16x32_bf16(aF[kb], bF, acc, 0, 0, 0);
        }
#pragma unroll
        for (int r = 0; r < 4; ++r)
            On[(size_t)(n0 + q * 4 + r) * HA + c0 + m] = f2b(fmaxf(acc[r], 0.f));
    }
}

// ---------------------------------------------------------------------------
// head2: fused readout (sorted amino_batch segmented sum over bf16 O) + MLP.
__global__ __launch_bounds__(256) void head2(
    const u16* __restrict__ O, size_t kstride, const int* __restrict__ bat,
    const float* __restrict__ l1w, const float* __restrict__ l1b,
    const float* __restrict__ l2w, const float* __restrict__ l2b,
    const float* __restrict__ l3w, const float* __restrict__ l3b,
    const float* __restrict__ l4w, const float* __restrict__ l4b,
    float* __restrict__ outp) {
    __shared__ float sg[HA], sp1[F1], sp2[F2], sp3[F3];
    int b = blockIdx.x, tx = threadIdx.x;
    int lo = 0, hi = N_AMINO;
    while (lo < hi) { int mid = (lo + hi) >> 1; if (bat[mid] < b) lo = mid + 1; else hi = mid; }
    int s = lo;
    lo = 0; hi = N_AMINO;
    while (lo < hi) { int mid = (lo + hi) >> 1; if (bat[mid] < b + 1) lo = mid + 1; else hi = mid; }
    int e = lo;
    if (tx < HA) {
        float acc = 0.f;
        for (int n = s; n < e; ++n)
            acc += b2f(O[(size_t)n * HA + tx]) + b2f(O[kstride + (size_t)n * HA + tx])
                 + b2f(O[2 * kstride + (size_t)n * HA + tx]);
        sg[tx] = acc * (1.f / 3.f);
    }
    __syncthreads();
    {   float acc = l1b[tx];
        for (int f = 0; f < HA; ++f) acc += sg[f] * l1w[f * F1 + tx];
        sp1[tx] = fmaxf(acc, 0.f); }
    __syncthreads();
    if (tx < F2) {
        float acc = l2b[tx];
        for (int f = 0; f < F1; ++f) acc += sp1[f] * l2w[f * F2 + tx];
        sp2[tx] = fmaxf(acc, 0.f); }
    __syncthreads();
    if (tx < F3) {
        float acc = l3b[tx];
        for (int f = 0; f < F2; ++f) acc += sp2[f] * l3w[f * F3 + tx];
        sp3[tx] = fmaxf(acc, 0.f); }
    __syncthreads();
    if (tx < 64) {
        float p = sp3[tx] * l4w[tx];
        for (int off = 32; off > 0; off >>= 1) p += __shfl_down(p, off, 64);
        if (tx == 0) outp[b] = p + l4b[0];
    }
}

// ---------------------------------------------------------------------------
// Workspace (<= 34,348,288 B, proven available).
#define OFF_M1    ((size_t)0)        // Mb1 bf16 34,816 B
#define OFF_M2    ((size_t)38400)    // Mb2 bf16 17,408 B
#define OFF_M3    ((size_t)57600)    // Mb3 bf16 17,408 B (ends 75,008)
#define OFF_AOFF  ((size_t)76800)
#define OFF_AEID  ((size_t)118016)
#define OFF_NRM   ((size_t)199936)
#define OFF_AA    ((size_t)281856)
#define OFF_HA    ((size_t)2891008)   // 4,000,000 -> 6,891,008
#define OFF_HB    ((size_t)6891008)   // 4,000,000 -> 10,891,008
#define OFF_MSG   ((size_t)10891008)  // 8,000,000 -> 18,891,008
#define OFF_SOFF  ((size_t)18891008)
#define OFF_DOFF  ((size_t)19291136)
#define OFF_DSLOT ((size_t)19691264)  // sdp: src-slot -> dst-pos
#define OFF_LOFF  ((size_t)20491264)
#define OFF_LNID  ((size_t)20532480)
#define OFF_CS    ((size_t)20932480)
#define OFF_CD    ((size_t)21332480)
#define OFF_CA    ((size_t)21732480)
#define OFF_CL    ((size_t)21773440)
#define OFF_US    ((size_t)21814400)
#define OFF_UD    ((size_t)22214400)
#define OFF_UA    ((size_t)22614400)
#define OFF_UL    ((size_t)22655360)
#define OFF_BSUM  ((size_t)22696320)
#define OFF_EAP   ((size_t)22697216)      // bf16x12 4,800,000 -> 27,497,216
#define OFF_SRCP  ((size_t)27497216)      // 800,000 -> 28,297,216
#define OFF_WP    ((size_t)28297216)      // 786,432 -> 29,083,648
#define OFF_SELFM ((size_t)29083648)      // bf16 4,000,000 -> 33,083,648
// ARMA overlays (NNConv buffers dead by then):
//   OB (odd-layer O): 2,891,008..10,755,328  (over hA/hB)
//   OA (even-layer O): 18,619,648..26,483,968 (over msg tail + eaP)
#define OFF_OB    ((size_t)2891008)
#define OFF_OA    ((size_t)18619648)

extern "C" void kernel_launch(void* const* d_in, const int* in_sizes, int n_in,
                              void* d_out, int out_size, void* d_ws, size_t ws_size,
                              hipStream_t stream) {
    (void)in_sizes; (void)n_in; (void)out_size; (void)ws_size;
    const float* x   = (const float*)d_in[0];
    const int*   ei  = (const int*)d_in[1];
    const float* ea  = (const float*)d_in[2];
    const int*   lbl = (const int*)d_in[3];
    const float* af  = (const float*)d_in[4];
    const int*   aei = (const int*)d_in[5];
    const int*   bat = (const int*)d_in[6];
    const float* nn1w = (const float*)d_in[7];  const float* nn1b = (const float*)d_in[8];
    const float* rt1  = (const float*)d_in[9];  const float* b1   = (const float*)d_in[10];
    const float* nn2w = (const float*)d_in[11]; const float* nn2b = (const float*)d_in[12];
    const float* rt2  = (const float*)d_in[13]; const float* b2   = (const float*)d_in[14];
    const float* nn3w = (const float*)d_in[15]; const float* nn3b = (const float*)d_in[16];
    const float* rt3  = (const float*)d_in[17]; const float* b3   = (const float*)d_in[18];
    const float* ai   = (const float*)d_in[19]; const float* aw   = (const float*)d_in[20];
    const float* arw  = (const float*)d_in[21]; const float* abi  = (const float*)d_in[22];
    const float* l1w  = (const float*)d_in[23]; const float* l1b  = (const float*)d_in[24];
    const float* l2w  = (const float*)d_in[25]; const float* l2b  = (const float*)d_in[26];
    const float* l3w  = (const float*)d_in[27]; const float* l3b  = (const float*)d_in[28];
    const float* l4w  = (const float*)d_in[29]; const float* l4b  = (const float*)d_in[30];
    float* outp = (float*)d_out;

    char* ws = (char*)d_ws;
    u16*   Mb1   = (u16*)(ws + OFF_M1);
    u16*   Mb2   = (u16*)(ws + OFF_M2);
    u16*   Mb3   = (u16*)(ws + OFF_M3);
    int*   aoff  = (int*)(ws + OFF_AOFF);
    int*   aeid  = (int*)(ws + OFF_AEID);
    float* nrm   = (float*)(ws + OFF_NRM);
    float* aa    = (float*)(ws + OFF_AA);
    u16*   hA    = (u16*)(ws + OFF_HA);
    u16*   hB    = (u16*)(ws + OFF_HB);
    u16*   msg   = (u16*)(ws + OFF_MSG);
    int*   soff  = (int*)(ws + OFF_SOFF);
    int*   doff  = (int*)(ws + OFF_DOFF);
    int*   sdp   = (int*)(ws + OFF_DSLOT);
    int*   loff  = (int*)(ws + OFF_LOFF);
    int*   lnid  = (int*)(ws + OFF_LNID);
    int*   cs    = (int*)(ws + OFF_CS);
    int*   cd    = (int*)(ws + OFF_CD);
    int*   ca    = (int*)(ws + OFF_CA);
    int*   cl    = (int*)(ws + OFF_CL);
    int*   us    = (int*)(ws + OFF_US);
    int*   ud    = (int*)(ws + OFF_UD);
    int*   ua    = (int*)(ws + OFF_UA);
    int*   ul    = (int*)(ws + OFF_UL);
    int*   bsum  = (int*)(ws + OFF_BSUM);
    u16*   eaP   = (u16*)(ws + OFF_EAP);
    int*   srcP  = (int*)(ws + OFF_SRCP);
    u16*   Wp    = (u16*)(ws + OFF_WP);
    u16*   selfm = (u16*)(ws + OFF_SELFM);
    u16*   OA    = (u16*)(ws + OFF_OA);
    u16*   OB    = (u16*)(ws + OFF_OB);

    const int* esrc = ei;
    const int* edst = ei + E_ATOMS;
    const int* adst = aei + E_AMINO;

    // prep (merged prep + weight pack)
    k_prep<<<(PREP_N + 255) / 256, 256, 0, stream>>>(
        nn1w, nn1b, rt1, nn2w, nn2b, rt2, nn3w, nn3b, rt3,
        Mb1, Mb2, Mb3, af, aa, cs, cd, ca, cl, ai, aw, arw, Wp);
    k_csr_count<<<(2 * E_ATOMS + E_AMINO + N_ATOMS + 255) / 256, 256, 0, stream>>>(
        esrc, edst, adst, lbl, cs, cd, ca, cl);
    k_scan1<<<2 * NBS + 2 * NBA, 256, 0, stream>>>(cs, soff, cd, doff, ca, aoff, cl, loff, bsum);
    k_scan2<<<4, 128, 0, stream>>>(bsum, soff, doff, aoff, loff);
    k_scan3<<<2 * NBS + 2 * NBA, 256, 0, stream>>>(soff, doff, aoff, loff, bsum, us, ud, ua, ul);
    k_csr_fill<<<(E_ATOMS + 2 * E_AMINO + N_ATOMS + 255) / 256, 256, 0, stream>>>(
        esrc, edst, ea, us, srcP, eaP, ud, sdp, aei, ua, aeid, aoff, nrm, lbl, ul, lnid);

    // NNConv (edge + separate streaming reduce; R11 lesson: do NOT fuse h)
    const int GT = N_ATOMS / NTILE;               // 6250
    const int GF = (N_ATOMS * HD + 255) / 256;    // 7813
    nnconv_edge13<DIN0, 2, true ><<<GT, 256, 0, stream>>>(x,  eaP, srcP, sdp, soff, Mb1, b1, msg, selfm);
    nnconv_reduce2<<<GF, 256, 0, stream>>>(selfm, doff, msg, hA);
    nnconv_edge13<HD,   1, false><<<GT, 256, 0, stream>>>(hA, eaP, srcP, sdp, soff, Mb2, b2, msg, selfm);
    nnconv_reduce2<<<GF, 256, 0, stream>>>(selfm, doff, msg, hB);
    nnconv_edge13<HD,   1, false><<<GT, 256, 0, stream>>>(hB, eaP, srcP, sdp, soff, Mb3, b3, msg, selfm);
    nnconv_reduce2<<<GF, 256, 0, stream>>>(selfm, doff, msg, hA);
    aa_gather<<<(N_AMINO * HD + 255) / 256, 256, 0, stream>>>(hA, loff, lnid, aa);

    // ARMA: gather/GEMM commuted; fused l0 (gather in LDS, 3 stacks); lt loop.
    const size_t KH = (size_t)N_AMINO * HA;
    arma_l0f<<<160, 256, 0, stream>>>(aa, aoff, aeid, aei, nrm, Wp, abi, OA, KH);
    for (int t = 1; t < TL; ++t) {
        const u16* Oin  = (t & 1) ? OA : OB;
        u16*       Oout = (t & 1) ? OB : OA;
        arma_lt<<<dim3(160, KS), 256, 0, stream>>>(
            Oin, Wp + WP0_ELEMS + (size_t)((t - 1) * KS) * 20480,
            abi + (size_t)t * KS * HA, aa, aoff, aeid, aei, nrm, Oout, KH);
    }
    // TL=7: final output (t=6, even) lands in OA.
    head2<<<NGRAPH, 256, 0, stream>>>(OA, KH, bat, l1w, l1b, l2w, l2b,
                                      l3w, l3b, l4w, l4b, outp);
}

// Round 15
// 495.071 us; speedup vs baseline: 1.0898x; 1.0898x over previous
//
#include <hip/hip_runtime.h>

#define N_ATOMS 100000
#define E_ATOMS 200000
#define N_AMINO 10240
#define E_AMINO 20480
#define NGRAPH 512
#define DIN0 40
#define D_E 11
#define HD 20
#define D_AA 8
#define HA 128
#define KS 3
#define TL 7
#define F1 256
#define F2 128
#define F3 64
#define NTILE 16  // nodes per edge-kernel tile (100000 % 16 == 0)
#define ECAP 64   // staged edges per chunk (mean 32/tile; loop handles overflow)
#define EAW 12    // eaP row (u16): 11 attrs + 1.0 pad; 24 B, u32-aligned

typedef unsigned short u16;
typedef unsigned int u32;
typedef __attribute__((ext_vector_type(8))) short short8;
typedef __attribute__((ext_vector_type(4))) float f32x4;

__device__ __forceinline__ float b2f(u16 u) {
    union { u32 i; float f; } v; v.i = ((u32)u) << 16; return v.f;
}
__device__ __forceinline__ u16 f2b(float f) {
    union { float f; u32 i; } v; v.f = f;
    u32 x = v.i;
    return (u16)((x + (((x >> 16) & 1u) + 0x7fffu)) >> 16);
}

// ---------------------------------------------------------------------------
// k_prep: merged prep + ARMA weight pack.
// Part A: Mb matrices in MFMA B-fragment order (bf16; 272 padded cols =
// W(220)|edge-bias(20)|root(20)|0(12), K padded to 32*KB) + aa feature cols
// + zero CSR counts.  Part B: ARMA weight pack (Wp).
#define MB1_ELEMS 17408   // DIN=40 -> KB=2, 2*8704
#define MB2_ELEMS 8704    // DIN=20 -> KB=1
#define PREP0_N (MB1_ELEMS + 2 * MB2_ELEMS + N_AMINO * D_AA + 2 * N_ATOMS + 2 * N_AMINO)
#define WP0_ELEMS (KS * 8192)
#define WP1_ELEMS (6 * KS * 20480)
#define PREP_N (PREP0_N + WP0_ELEMS + WP1_ELEMS)
__global__ __launch_bounds__(256) void k_prep(
    const float* __restrict__ w1, const float* __restrict__ nb1, const float* __restrict__ r1,
    const float* __restrict__ w2, const float* __restrict__ nb2, const float* __restrict__ r2,
    const float* __restrict__ w3, const float* __restrict__ nb3, const float* __restrict__ r3,
    u16* __restrict__ Mb1, u16* __restrict__ Mb2, u16* __restrict__ Mb3,
    const float* __restrict__ af, float* __restrict__ aa,
    int* __restrict__ cs, int* __restrict__ cd,
    int* __restrict__ ca, int* __restrict__ cl,
    const float* __restrict__ ai, const float* __restrict__ aw,
    const float* __restrict__ arw, u16* __restrict__ Wp) {
    int t = blockIdx.x * 256 + threadIdx.x;
    if (t < MB1_ELEMS) {
        int kb = t / 8704, rem = t % 8704;
        int c = rem >> 5, qj = rem & 31;
        int krow = kb * 32 + qj;
        float v = 0.f;
        if (krow < DIN0) {
            if (c < 220)      v = w1[(c / 20) * 800 + krow * 20 + (c % 20)];
            else if (c < 240) v = nb1[krow * 20 + (c - 220)];
            else if (c < 260) v = r1[krow * 20 + (c - 240)];
        }
        Mb1[t] = f2b(v);
    } else if (t < MB1_ELEMS + MB2_ELEMS) {
        int tt = t - MB1_ELEMS;
        int c = tt >> 5, qj = tt & 31;
        float v = 0.f;
        if (qj < HD) {
            if (c < 220)      v = w2[(c / 20) * 400 + qj * 20 + (c % 20)];
            else if (c < 240) v = nb2[qj * 20 + (c - 220)];
            else if (c < 260) v = r2[qj * 20 + (c - 240)];
        }
        Mb2[tt] = f2b(v);
    } else if (t < MB1_ELEMS + 2 * MB2_ELEMS) {
        int tt = t - MB1_ELEMS - MB2_ELEMS;
        int c = tt >> 5, qj = tt & 31;
        float v = 0.f;
        if (qj < HD) {
            if (c < 220)      v = w3[(c / 20) * 400 + qj * 20 + (c % 20)];
            else if (c < 240) v = nb3[qj * 20 + (c - 220)];
            else if (c < 260) v = r3[qj * 20 + (c - 240)];
        }
        Mb3[tt] = f2b(v);
    } else if (t < MB1_ELEMS + 2 * MB2_ELEMS + N_AMINO * D_AA) {
        int idx = t - MB1_ELEMS - 2 * MB2_ELEMS, m = idx / D_AA, j = idx % D_AA;
        aa[m * 28 + HD + j] = af[idx];
    } else if (t < PREP0_N) {
        int z = t - MB1_ELEMS - 2 * MB2_ELEMS - N_AMINO * D_AA;
        if (z < N_ATOMS) cs[z] = 0;
        else if (z < 2 * N_ATOMS) cd[z - N_ATOMS] = 0;
        else if (z < 2 * N_ATOMS + N_AMINO) ca[z - 2 * N_ATOMS] = 0;
        else if (z < 2 * N_ATOMS + 2 * N_AMINO) cl[z - 2 * N_ATOMS - N_AMINO] = 0;
    } else {
        int g = t - PREP0_N;
        if (g < WP0_ELEMS) {
            int k = g / 8192, r = g % 8192;
            int kb = r >> 12, rem = r & 4095;
            int c = rem >> 5, qj = rem & 31;
            int krow = kb * 32 + qj;
            float v = 0.f;
            if (krow < 28)      v = ai[((size_t)k * 28 + krow) * HA + c];
            else if (krow < 56) v = arw[((size_t)k * 28 + (krow - 28)) * HA + c];
            Wp[g] = f2b(v);
        } else if (g < WP0_ELEMS + WP1_ELEMS) {
            int gg = g - WP0_ELEMS;
            int mat = gg / 20480, r = gg % 20480;
            int kb = r / 4096, rem = r & 4095;
            int c = rem >> 5, qj = rem & 31;
            int krow = kb * 32 + qj;
            int tm1 = mat / KS, k = mat % KS;
            float v = 0.f;
            if (krow < 128)      v = aw[((size_t)mat * 128 + krow) * HA + c];
            else if (krow < 156) v = arw[(((size_t)(tm1 + 1) * KS + k) * 28 + (krow - 128)) * HA + c];
            Wp[g] = f2b(v);
        }
    }
}

// ---------------------------------------------------------------------------
#define NBS 98
#define NBA 10

__global__ __launch_bounds__(256) void k_csr_count(
    const int* __restrict__ esrc, const int* __restrict__ edst,
    const int* __restrict__ adst, const int* __restrict__ lbl,
    int* __restrict__ cs, int* __restrict__ cd,
    int* __restrict__ ca, int* __restrict__ cl) {
    int t = blockIdx.x * 256 + threadIdx.x;
    if (t < E_ATOMS) atomicAdd(cs + esrc[t], 1);
    else if (t < 2 * E_ATOMS) atomicAdd(cd + edst[t - E_ATOMS], 1);
    else if (t < 2 * E_ATOMS + E_AMINO) atomicAdd(ca + adst[t - 2 * E_ATOMS], 1);
    else if (t < 2 * E_ATOMS + E_AMINO + N_ATOMS) atomicAdd(cl + lbl[t - 2 * E_ATOMS - E_AMINO], 1);
}
__device__ __forceinline__ void seg_decode(int bx, int* blk, int* n, int* which) {
    if (bx < NBS)            { *which = 0; *blk = bx;             *n = N_ATOMS; }
    else if (bx < 2 * NBS)   { *which = 1; *blk = bx - NBS;       *n = N_ATOMS; }
    else if (bx < 2 * NBS + NBA) { *which = 2; *blk = bx - 2 * NBS; *n = N_AMINO; }
    else                     { *which = 3; *blk = bx - 2 * NBS - NBA; *n = N_AMINO; }
}
__global__ __launch_bounds__(256) void k_scan1(
    const int* __restrict__ cs, int* __restrict__ soff,
    const int* __restrict__ cd, int* __restrict__ doff,
    const int* __restrict__ ca, int* __restrict__ aoff,
    const int* __restrict__ cl, int* __restrict__ loff,
    int* __restrict__ bsum) {
    int blk, n, which;
    seg_decode(blockIdx.x, &blk, &n, &which);
    const int* c = which == 0 ? cs : which == 1 ? cd : which == 2 ? ca : cl;
    int* o = which == 0 ? soff : which == 1 ? doff : which == 2 ? aoff : loff;
    int tx = threadIdx.x, lane = tx & 63, w = tx >> 6;
    int i0 = blk * 1024 + tx * 4;
    int v[4];
#pragma unroll
    for (int q = 0; q < 4; ++q) v[q] = (i0 + q < n) ? c[i0 + q] : 0;
    int s = v[0] + v[1] + v[2] + v[3];
    int inc = s;
#pragma unroll
    for (int d = 1; d < 64; d <<= 1) {
        int u = __shfl_up(inc, d, 64);
        if (lane >= d) inc += u;
    }
    __shared__ int wsum[4];
    if (lane == 63) wsum[w] = inc;
    __syncthreads();
    int wo = 0;
    for (int i = 0; i < w; ++i) wo += wsum[i];
    int run = wo + inc - s;
#pragma unroll
    for (int q = 0; q < 4; ++q) {
        if (i0 + q < n) o[i0 + q] = run;
        run += v[q];
    }
    if (tx == 255) bsum[blockIdx.x] = wo + inc;
}
__global__ __launch_bounds__(128) void k_scan2(
    int* __restrict__ bsum, int* __restrict__ soff, int* __restrict__ doff,
    int* __restrict__ aoff, int* __restrict__ loff) {
    int bx = blockIdx.x;
    int nb   = (bx < 2) ? NBS : NBA;
    int base = (bx == 0) ? 0 : (bx == 1) ? NBS : (bx == 2) ? 2 * NBS : 2 * NBS + NBA;
    int* b = bsum + base;
    int tx = threadIdx.x, lane = tx & 63;
    int v = (tx < nb) ? b[tx] : 0;
    int inc = v;
#pragma unroll
    for (int d = 1; d < 64; d <<= 1) {
        int u = __shfl_up(inc, d, 64);
        if (lane >= d) inc += u;
    }
    __shared__ int w0;
    if (tx == 63) w0 = inc;
    __syncthreads();
    int excl = inc - v + ((tx >= 64) ? w0 : 0);
    if (tx < nb) b[tx] = excl;
    if (tx == nb - 1) {
        int tot = excl + v;
        if (bx == 0) soff[N_ATOMS] = tot;
        else if (bx == 1) doff[N_ATOMS] = tot;
        else if (bx == 2) aoff[N_AMINO] = tot;
        else loff[N_AMINO] = tot;
    }
}
__global__ __launch_bounds__(256) void k_scan3(
    int* __restrict__ soff, int* __restrict__ doff,
    int* __restrict__ aoff, int* __restrict__ loff,
    const int* __restrict__ bsum,
    int* __restrict__ us, int* __restrict__ ud,
    int* __restrict__ ua, int* __restrict__ ul) {
    int blk, n, which;
    seg_decode(blockIdx.x, &blk, &n, &which);
    int* o = which == 0 ? soff : which == 1 ? doff : which == 2 ? aoff : loff;
    int* cu = which == 0 ? us : which == 1 ? ud : which == 2 ? ua : ul;
    int add = bsum[blockIdx.x];
    int i0 = blk * 1024 + threadIdx.x * 4;
#pragma unroll
    for (int q = 0; q < 4; ++q)
        if (i0 + q < n) { int val = o[i0 + q] + add; o[i0 + q] = val; cu[i0 + q] = val; }
}
// fill: src slots -> srcP/eaP(bf16 x11 + 1.0 pad) + sdp (src-slot -> dst-pos),
// amino eids+nrm, label->node
__global__ __launch_bounds__(256) void k_csr_fill(
    const int* __restrict__ esrc, const int* __restrict__ edst,
    const float* __restrict__ ea,
    int* __restrict__ us, int* __restrict__ srcP, u16* __restrict__ eaP,
    int* __restrict__ ud, int* __restrict__ sdp,
    const int* __restrict__ aei, int* __restrict__ ua, int* __restrict__ aeid,
    const int* __restrict__ aoff, float* __restrict__ nrm,
    const int* __restrict__ lbl, int* __restrict__ ul, int* __restrict__ lnid) {
    int t = blockIdx.x * 256 + threadIdx.x;
    if (t < E_ATOMS) {
        int jj = atomicAdd(us + esrc[t], 1);
        srcP[jj] = esrc[t];
        const float* e0 = ea + (size_t)t * D_E;
        u16* e1 = eaP + (size_t)jj * EAW;
#pragma unroll
        for (int k = 0; k < D_E; ++k) e1[k] = f2b(e0[k]);
        e1[D_E] = f2b(1.0f);   // pad = 1.0: folds edge-MLP bias into the 12-dot
        sdp[jj] = atomicAdd(ud + edst[t], 1);   // dst-CSR position for this edge
    } else if (t < E_ATOMS + E_AMINO) {
        int e = t - E_ATOMS;
        int p = atomicAdd(ua + aei[E_AMINO + e], 1);
        aeid[p] = e;
    } else if (t < E_ATOMS + 2 * E_AMINO) {
        int e = t - E_ATOMS - E_AMINO;
        int s = aei[e], d = aei[E_AMINO + e];
        int ds = aoff[s + 1] - aoff[s], dd = aoff[d + 1] - aoff[d];
        float a = ds > 0 ? rsqrtf((float)ds) : 0.f;
        float b = dd > 0 ? rsqrtf((float)dd) : 0.f;
        nrm[e] = a * b;
    } else if (t < E_ATOMS + 2 * E_AMINO + N_ATOMS) {
        int n = t - E_ATOMS - 2 * E_AMINO;
        int p = atomicAdd(ul + lbl[n], 1);
        lnid[p] = n;
    }
}

// ---------------------------------------------------------------------------
// NNConv edge v11 (restored verbatim from the 469-us build): MFMA phase-1
// over 17 col-tiles (240 msg-dot cols -> packed y3; 20 root cols -> selfm =
// x@root + bias). Phase 2: 20 lanes/edge, scalar u16 store, dst-ordered msg.
// R12 lesson: the 2-output u32 phase-2 variant regressed this kernel
// 44 -> 61.5 us (WRITE 79 MB, bank conflicts 3x); do not reapply without
// a counter-verified A/B.
template <int DIN, int KB, bool RAW>
__global__ __launch_bounds__(256, 6) void nnconv_edge11(
    const void* __restrict__ xin, const u16* __restrict__ eaP,
    const int* __restrict__ srcP, const int* __restrict__ sdp,
    const int* __restrict__ soff, const u16* __restrict__ Mb,
    const float* __restrict__ bnn, u16* __restrict__ msg,
    u16* __restrict__ selfm) {
    constexpr int KPAD = KB * 32;
    __shared__ __align__(16) float y3[NTILE * 240];
    __shared__ __align__(16) u16 As[NTILE * KPAD];
    __shared__ __align__(16) float eaS[ECAP * 12];
    __shared__ int srcS[ECAP];
    __shared__ int sdpS[ECAP];
    int tx = threadIdx.x;
    int n0 = blockIdx.x * NTILE;         // N_ATOMS % NTILE == 0
    int j0 = soff[n0], j1 = soff[n0 + NTILE];
    // stage X as bf16 A-fragments (node-major rows, zero-pad k >= DIN)
    for (int i = tx; i < NTILE * KPAD; i += 256) {
        int node = i / KPAD, k = i % KPAD;
        u16 v = 0;
        if (k < DIN)
            v = RAW ? f2b(((const float*)xin)[(size_t)(n0 + node) * DIN + k])
                    : ((const u16*)xin)[(size_t)(n0 + node) * DIN + k];
        As[i] = v;
    }
    // stage phase-2 chunk 0
    {
        int cn0 = j1 - j0; if (cn0 > ECAP) cn0 = ECAP;
        for (int i = tx; i < cn0; i += 256) {
            srcS[i] = srcP[j0 + i] - n0;
            sdpS[i] = sdp[j0 + i];
        }
        const u32* eg = (const u32*)(eaP + (size_t)j0 * EAW);
        for (int i = tx; i < cn0 * 6; i += 256) {
            u32 pv = eg[i];
            eaS[2 * i]     = b2f((u16)(pv & 0xffff));
            eaS[2 * i + 1] = b2f((u16)(pv >> 16));
        }
    }
    __syncthreads();
    // phase 1: MFMA over 17 col-tiles; wave handles ct = wave, wave+4, ...
    {
        int wave = tx >> 6, lane = tx & 63;
        int m = lane & 15, q = lane >> 4;
        short8 aF[KB];
#pragma unroll
        for (int kb = 0; kb < KB; ++kb)
            aF[kb] = *(const short8*)&As[m * KPAD + kb * 32 + q * 8];
        for (int ct = wave; ct < 17; ct += 4) {
            int c0 = ct * 16;
            f32x4 acc = {0.f, 0.f, 0.f, 0.f};
#pragma unroll
            for (int kb = 0; kb < KB; ++kb) {
                short8 bF = *(const short8*)(Mb + (size_t)kb * 8704 + (size_t)(c0 + m) * 32 + q * 8);
                acc = __builtin_amdgcn_mfma_f32_16x16x32_bf16(aF[kb], bF, acc, 0, 0, 0);
            }
            int c = c0 + m;
            if (c < 240) {
                int slot = (c < 220) ? (c % 20) * 12 + c / 20 : (c - 220) * 12 + 11;
#pragma unroll
                for (int r = 0; r < 4; ++r)
                    y3[(q * 4 + r) * 240 + slot] = acc[r];
            } else if (c < 260) {
                float bv = bnn[c - 240];
#pragma unroll
                for (int r = 0; r < 4; ++r)
                    selfm[(size_t)(n0 + q * 4 + r) * HD + (c - 240)] = f2b(acc[r] + bv);
            }
        }
    }
    __syncthreads();
    // phase 2: LDS-only; task p = (edge e, out o); 12-dot; msg in dst order
    int c0 = j0;
    while (true) {
        int cn = j1 - c0; if (cn > ECAP) cn = ECAP;
        for (int p = tx; p < cn * 20; p += 256) {
            int e = p / 20, o = p - e * 20;
            const float4* ev = (const float4*)&eaS[e * 12];
            const float4* yr = (const float4*)&y3[srcS[e] * 240 + o * 12];
            float4 e0 = ev[0], e1 = ev[1], e2 = ev[2];
            float4 q0 = yr[0], q1 = yr[1], q2 = yr[2];
            float mv = e0.x * q0.x + e0.y * q0.y + e0.z * q0.z + e0.w * q0.w
                     + e1.x * q1.x + e1.y * q1.y + e1.z * q1.z + e1.w * q1.w
                     + e2.x * q2.x + e2.y * q2.y + e2.z * q2.z + e2.w * q2.w;
            msg[(size_t)sdpS[e] * 20 + o] = f2b(mv);
        }
        c0 += cn;
        if (c0 >= j1) break;
        // rare: tile had >ECAP edges — restage next chunk
        __syncthreads();
        int cm = j1 - c0; if (cm > ECAP) cm = ECAP;
        for (int i = tx; i < cm; i += 256) {
            srcS[i] = srcP[c0 + i] - n0;
            sdpS[i] = sdp[c0 + i];
        }
        const u32* eg = (const u32*)(eaP + (size_t)c0 * EAW);
        for (int i = tx; i < cm * 6; i += 256) {
            u32 pv = eg[i];
            eaS[2 * i]     = b2f((u16)(pv & 0xffff));
            eaS[2 * i + 1] = b2f((u16)(pv >> 16));
        }
        __syncthreads();
    }
}

// NNConv reduce v2: pure streaming. h = relu(selfm + sum of contiguous
// dst-ordered msg rows). No x, no root, no indirection.
__global__ __launch_bounds__(256) void nnconv_reduce2(
    const u16* __restrict__ selfm, const int* __restrict__ doff,
    const u16* __restrict__ msg, u16* __restrict__ hout) {
    int t = blockIdx.x * 256 + threadIdx.x;
    if (t >= N_ATOMS * HD) return;
    int n = t / HD, o = t - n * HD;
    float acc = b2f(selfm[t]);
    int j1 = doff[n + 1];
    for (int j = doff[n]; j < j1; ++j)
        acc += b2f(msg[(size_t)j * HD + o]);
    hout[t] = f2b(fmaxf(acc, 0.f));
}

// aa gather: label-CSR segmented sum of h3
__global__ __launch_bounds__(256) void aa_gather(
    const u16* __restrict__ h3, const int* __restrict__ loff,
    const int* __restrict__ lnid, float* __restrict__ aa) {
    int t = blockIdx.x * 256 + threadIdx.x;
    if (t >= N_AMINO * HD) return;
    int m = t / HD, o = t % HD;
    float s = 0.f;
    int j1 = loff[m + 1];
    for (int j = loff[m]; j < j1; ++j)
        s += b2f(h3[(size_t)lnid[j] * HD + o]);
    aa[m * 28 + o] = s;
}

// ---------------------------------------------------------------------------
// ARMA layer 0 fused: gather A0-tile = [gather(aa)(28)|aa(28)|0(8)] into LDS,
// then O_k = relu(A0 @ [init_k;root0_k] + bias_k) for all 3 stacks via MFMA.
__global__ __launch_bounds__(256) void arma_l0f(
    const float* __restrict__ aa, const int* __restrict__ aoff,
    const int* __restrict__ aeid, const int* __restrict__ aei,
    const float* __restrict__ nrm, const u16* __restrict__ Wp0,
    const float* __restrict__ abi, u16* __restrict__ O, size_t kstride) {
    __shared__ __align__(16) u16 As[64 * 64];
    int tx = threadIdx.x;
    int n0b = blockIdx.x * 64;
    for (int i = tx; i < 64 * 64; i += 256) {
        int nl = i >> 6, c = i & 63;
        int n = n0b + nl;
        float v = 0.f;
        if (c < 28) {
            int j1 = aoff[n + 1];
            for (int jj = aoff[n]; jj < j1; ++jj) {
                int e = aeid[jj], s = aei[e];
                v += nrm[e] * aa[(size_t)s * 28 + c];
            }
        } else if (c < 56) {
            v = aa[(size_t)n * 28 + (c - 28)];
        }
        As[i] = f2b(v);
    }
    __syncthreads();
    int wave = tx >> 6, lane = tx & 63;
    int m = lane & 15, q = lane >> 4;
    short8 aF[2];
#pragma unroll
    for (int kb = 0; kb < 2; ++kb)
        aF[kb] = *(const short8*)&As[(wave * 16 + m) * 64 + kb * 32 + q * 8];
    int n0 = n0b + wave * 16;
    for (int k = 0; k < KS; ++k) {
        const u16* W = Wp0 + (size_t)k * 8192;
        u16* Ok = O + (size_t)k * kstride;
        const float* bk = abi + (size_t)k * HA;   // abi[t=0][k][:]
#pragma unroll
        for (int ct = 0; ct < 8; ++ct) {
            int c0 = ct * 16;
            float b = bk[c0 + m];
            f32x4 acc = {b, b, b, b};
#pragma unroll
            for (int kb = 0; kb < 2; ++kb) {
                short8 bF = *(const short8*)(W + (size_t)((kb * 128 + c0 + m) * 32 + q * 8));
                acc = __builtin_amdgcn_mfma_f32_16x16x32_bf16(aF[kb], bF, acc, 0, 0, 0);
            }
#pragma unroll
            for (int r = 0; r < 4; ++r)
                Ok[(size_t)(n0 + q * 4 + r) * HA + c0 + m] = f2b(fmaxf(acc[r], 0.f));
        }
    }
}

// ARMA layer t>=1 fused: gather G=sum nrm*Oprev[src] into LDS (+aa cols),
// then O = relu([G|aa] @ [W;root] + bias) via MFMA (K=160). 64-node tiles.
__global__ __launch_bounds__(256) void arma_lt(
    const u16* __restrict__ Oprev, const u16* __restrict__ Wm,
    const float* __restrict__ abit, const float* __restrict__ aa,
    const int* __restrict__ aoff, const int* __restrict__ aeid,
    const int* __restrict__ aei, const float* __restrict__ nrm,
    u16* __restrict__ Onext, size_t kstride) {
    __shared__ __align__(16) u16 As[64 * 160];
    int tx = threadIdx.x;
    int k = blockIdx.y;
    int n0b = blockIdx.x * 64;
    const u16* Op = Oprev + (size_t)k * kstride;
    const u16* W  = Wm + (size_t)k * 20480;   // per-stack weight offset
    // gather phase: 1024 tasks = 64 nodes x 16 col-blocks (8 bf16 each)
    for (int i = tx; i < 1024; i += 256) {
        int nl = i >> 4, cb = i & 15;
        int n = n0b + nl;
        int j1 = aoff[n + 1];
        float a0 = 0.f, a1 = 0.f, a2 = 0.f, a3 = 0.f;
        float a4 = 0.f, a5 = 0.f, a6 = 0.f, a7 = 0.f;
        for (int jj = aoff[n]; jj < j1; ++jj) {
            int e = aeid[jj], s = aei[e];
            float nm = nrm[e];
            uint4 hv = *(const uint4*)(Op + (size_t)s * HA + cb * 8);
            a0 += nm * b2f((u16)(hv.x & 0xffff));
            a1 += nm * b2f((u16)(hv.x >> 16));
            a2 += nm * b2f((u16)(hv.y & 0xffff));
            a3 += nm * b2f((u16)(hv.y >> 16));
            a4 += nm * b2f((u16)(hv.z & 0xffff));
            a5 += nm * b2f((u16)(hv.z >> 16));
            a6 += nm * b2f((u16)(hv.w & 0xffff));
            a7 += nm * b2f((u16)(hv.w >> 16));
        }
        uint4 pk;
        pk.x = (u32)f2b(a0) | ((u32)f2b(a1) << 16);
        pk.y = (u32)f2b(a2) | ((u32)f2b(a3) << 16);
        pk.z = (u32)f2b(a4) | ((u32)f2b(a5) << 16);
        pk.w = (u32)f2b(a6) | ((u32)f2b(a7) << 16);
        *(uint4*)&As[nl * 160 + cb * 8] = pk;
    }
    // aa cols 128..159: 256 tasks = 64 nodes x 4 col-blocks
    {
        int nl = tx >> 2, cb = tx & 3;
        int n = n0b + nl;
        float av[8];
#pragma unroll
        for (int j = 0; j < 8; ++j) {
            int c = cb * 8 + j;
            av[j] = (c < 28) ? aa[(size_t)n * 28 + c] : 0.f;
        }
        uint4 pk;
        pk.x = (u32)f2b(av[0]) | ((u32)f2b(av[1]) << 16);
        pk.y = (u32)f2b(av[2]) | ((u32)f2b(av[3]) << 16);
        pk.z = (u32)f2b(av[4]) | ((u32)f2b(av[5]) << 16);
        pk.w = (u32)f2b(av[6]) | ((u32)f2b(av[7]) << 16);
        *(uint4*)&As[nl * 160 + 128 + cb * 8] = pk;
    }
    __syncthreads();
    // MFMA phase: wave w -> rows n0b + w*16 .. +16, K = 160 (5 kb-blocks)
    int wave = tx >> 6, lane = tx & 63;
    int m = lane & 15, q = lane >> 4;
    int wl = wave * 16 + m;
    short8 aF[5];
#pragma unroll
    for (int kb = 0; kb < 5; ++kb)
        aF[kb] = *(const short8*)&As[wl * 160 + kb * 32 + q * 8];
    int n0 = n0b + wave * 16;
    u16* On = Onext + (size_t)k * kstride;
    const float* bk = abit + (size_t)k * HA;
#pragma unroll
    for (int ct = 0; ct < 8; ++ct) {
        int c0 = ct * 16;
        float b = bk[c0 + m];
        f32x4 acc = {b, b, b, b};
#pragma unroll
        for (int kb = 0; kb < 5; ++kb) {
            short8 bF = *(const short8*)(W + (size_t)((kb * 128 + c0 + m) * 32 + q * 8));
            acc = __builtin_amdgcn_mfma_f32_16x16x32_bf16(aF[kb], bF, acc, 0, 0, 0);
        }
#pragma unroll
        for (int r = 0; r < 4; ++r)
            On[(size_t)(n0 + q * 4 + r) * HA + c0 + m] = f2b(fmaxf(acc[r], 0.f));
    }
}

// ---------------------------------------------------------------------------
// head2: fused readout (sorted amino_batch segmented sum over bf16 O) + MLP.
__global__ __launch_bounds__(256) void head2(
    const u16* __restrict__ O, size_t kstride, const int* __restrict__ bat,
    const float* __restrict__ l1w, const float* __restrict__ l1b,
    const float* __restrict__ l2w, const float* __restrict__ l2b,
    const float* __restrict__ l3w, const float* __restrict__ l3b,
    const float* __restrict__ l4w, const float* __restrict__ l4b,
    float* __restrict__ outp) {
    __shared__ float sg[HA], sp1[F1], sp2[F2], sp3[F3];
    int b = blockIdx.x, tx = threadIdx.x;
    int lo = 0, hi = N_AMINO;
    while (lo < hi) { int mid = (lo + hi) >> 1; if (bat[mid] < b) lo = mid + 1; else hi = mid; }
    int s = lo;
    lo = 0; hi = N_AMINO;
    while (lo < hi) { int mid = (lo + hi) >> 1; if (bat[mid] < b + 1) lo = mid + 1; else hi = mid; }
    int e = lo;
    if (tx < HA) {
        float acc = 0.f;
        for (int n = s; n < e; ++n)
            acc += b2f(O[(size_t)n * HA + tx]) + b2f(O[kstride + (size_t)n * HA + tx])
                 + b2f(O[2 * kstride + (size_t)n * HA + tx]);
        sg[tx] = acc * (1.f / 3.f);
    }
    __syncthreads();
    {   float acc = l1b[tx];
        for (int f = 0; f < HA; ++f) acc += sg[f] * l1w[f * F1 + tx];
        sp1[tx] = fmaxf(acc, 0.f); }
    __syncthreads();
    if (tx < F2) {
        float acc = l2b[tx];
        for (int f = 0; f < F1; ++f) acc += sp1[f] * l2w[f * F2 + tx];
        sp2[tx] = fmaxf(acc, 0.f); }
    __syncthreads();
    if (tx < F3) {
        float acc = l3b[tx];
        for (int f = 0; f < F2; ++f) acc += sp2[f] * l3w[f * F3 + tx];
        sp3[tx] = fmaxf(acc, 0.f); }
    __syncthreads();
    if (tx < 64) {
        float p = sp3[tx] * l4w[tx];
        for (int off = 32; off > 0; off >>= 1) p += __shfl_down(p, off, 64);
        if (tx == 0) outp[b] = p + l4b[0];
    }
}

// ---------------------------------------------------------------------------
// Workspace (<= 34,348,288 B, proven available).
#define OFF_M1    ((size_t)0)        // Mb1 bf16 34,816 B
#define OFF_M2    ((size_t)38400)    // Mb2 bf16 17,408 B
#define OFF_M3    ((size_t)57600)    // Mb3 bf16 17,408 B (ends 75,008)
#define OFF_AOFF  ((size_t)76800)
#define OFF_AEID  ((size_t)118016)
#define OFF_NRM   ((size_t)199936)
#define OFF_AA    ((size_t)281856)
#define OFF_HA    ((size_t)2891008)   // 4,000,000 -> 6,891,008
#define OFF_HB    ((size_t)6891008)   // 4,000,000 -> 10,891,008
#define OFF_MSG   ((size_t)10891008)  // 8,000,000 -> 18,891,008
#define OFF_SOFF  ((size_t)18891008)
#define OFF_DOFF  ((size_t)19291136)
#define OFF_DSLOT ((size_t)19691264)  // sdp: src-slot -> dst-pos
#define OFF_LOFF  ((size_t)20491264)
#define OFF_LNID  ((size_t)20532480)
#define OFF_CS    ((size_t)20932480)
#define OFF_CD    ((size_t)21332480)
#define OFF_CA    ((size_t)21732480)
#define OFF_CL    ((size_t)21773440)
#define OFF_US    ((size_t)21814400)
#define OFF_UD    ((size_t)22214400)
#define OFF_UA    ((size_t)22614400)
#define OFF_UL    ((size_t)22655360)
#define OFF_BSUM  ((size_t)22696320)
#define OFF_EAP   ((size_t)22697216)      // bf16x12 4,800,000 -> 27,497,216
#define OFF_SRCP  ((size_t)27497216)      // 800,000 -> 28,297,216
#define OFF_WP    ((size_t)28297216)      // 786,432 -> 29,083,648
#define OFF_SELFM ((size_t)29083648)      // bf16 4,000,000 -> 33,083,648
// ARMA overlays (NNConv buffers dead by then):
//   OB (odd-layer O): 2,891,008..10,755,328  (over hA/hB)
//   OA (even-layer O): 18,619,648..26,483,968 (over msg tail + eaP)
#define OFF_OB    ((size_t)2891008)
#define OFF_OA    ((size_t)18619648)

extern "C" void kernel_launch(void* const* d_in, const int* in_sizes, int n_in,
                              void* d_out, int out_size, void* d_ws, size_t ws_size,
                              hipStream_t stream) {
    (void)in_sizes; (void)n_in; (void)out_size; (void)ws_size;
    const float* x   = (const float*)d_in[0];
    const int*   ei  = (const int*)d_in[1];
    const float* ea  = (const float*)d_in[2];
    const int*   lbl = (const int*)d_in[3];
    const float* af  = (const float*)d_in[4];
    const int*   aei = (const int*)d_in[5];
    const int*   bat = (const int*)d_in[6];
    const float* nn1w = (const float*)d_in[7];  const float* nn1b = (const float*)d_in[8];
    const float* rt1  = (const float*)d_in[9];  const float* b1   = (const float*)d_in[10];
    const float* nn2w = (const float*)d_in[11]; const float* nn2b = (const float*)d_in[12];
    const float* rt2  = (const float*)d_in[13]; const float* b2   = (const float*)d_in[14];
    const float* nn3w = (const float*)d_in[15]; const float* nn3b = (const float*)d_in[16];
    const float* rt3  = (const float*)d_in[17]; const float* b3   = (const float*)d_in[18];
    const float* ai   = (const float*)d_in[19]; const float* aw   = (const float*)d_in[20];
    const float* arw  = (const float*)d_in[21]; const float* abi  = (const float*)d_in[22];
    const float* l1w  = (const float*)d_in[23]; const float* l1b  = (const float*)d_in[24];
    const float* l2w  = (const float*)d_in[25]; const float* l2b  = (const float*)d_in[26];
    const float* l3w  = (const float*)d_in[27]; const float* l3b  = (const float*)d_in[28];
    const float* l4w  = (const float*)d_in[29]; const float* l4b  = (const float*)d_in[30];
    float* outp = (float*)d_out;

    char* ws = (char*)d_ws;
    u16*   Mb1   = (u16*)(ws + OFF_M1);
    u16*   Mb2   = (u16*)(ws + OFF_M2);
    u16*   Mb3   = (u16*)(ws + OFF_M3);
    int*   aoff  = (int*)(ws + OFF_AOFF);
    int*   aeid  = (int*)(ws + OFF_AEID);
    float* nrm   = (float*)(ws + OFF_NRM);
    float* aa    = (float*)(ws + OFF_AA);
    u16*   hA    = (u16*)(ws + OFF_HA);
    u16*   hB    = (u16*)(ws + OFF_HB);
    u16*   msg   = (u16*)(ws + OFF_MSG);
    int*   soff  = (int*)(ws + OFF_SOFF);
    int*   doff  = (int*)(ws + OFF_DOFF);
    int*   sdp   = (int*)(ws + OFF_DSLOT);
    int*   loff  = (int*)(ws + OFF_LOFF);
    int*   lnid  = (int*)(ws + OFF_LNID);
    int*   cs    = (int*)(ws + OFF_CS);
    int*   cd    = (int*)(ws + OFF_CD);
    int*   ca    = (int*)(ws + OFF_CA);
    int*   cl    = (int*)(ws + OFF_CL);
    int*   us    = (int*)(ws + OFF_US);
    int*   ud    = (int*)(ws + OFF_UD);
    int*   ua    = (int*)(ws + OFF_UA);
    int*   ul    = (int*)(ws + OFF_UL);
    int*   bsum  = (int*)(ws + OFF_BSUM);
    u16*   eaP   = (u16*)(ws + OFF_EAP);
    int*   srcP  = (int*)(ws + OFF_SRCP);
    u16*   Wp    = (u16*)(ws + OFF_WP);
    u16*   selfm = (u16*)(ws + OFF_SELFM);
    u16*   OA    = (u16*)(ws + OFF_OA);
    u16*   OB    = (u16*)(ws + OFF_OB);

    const int* esrc = ei;
    const int* edst = ei + E_ATOMS;
    const int* adst = aei + E_AMINO;

    // prep (merged prep + weight pack)
    k_prep<<<(PREP_N + 255) / 256, 256, 0, stream>>>(
        nn1w, nn1b, rt1, nn2w, nn2b, rt2, nn3w, nn3b, rt3,
        Mb1, Mb2, Mb3, af, aa, cs, cd, ca, cl, ai, aw, arw, Wp);
    k_csr_count<<<(2 * E_ATOMS + E_AMINO + N_ATOMS + 255) / 256, 256, 0, stream>>>(
        esrc, edst, adst, lbl, cs, cd, ca, cl);
    k_scan1<<<2 * NBS + 2 * NBA, 256, 0, stream>>>(cs, soff, cd, doff, ca, aoff, cl, loff, bsum);
    k_scan2<<<4, 128, 0, stream>>>(bsum, soff, doff, aoff, loff);
    k_scan3<<<2 * NBS + 2 * NBA, 256, 0, stream>>>(soff, doff, aoff, loff, bsum, us, ud, ua, ul);
    k_csr_fill<<<(E_ATOMS + 2 * E_AMINO + N_ATOMS + 255) / 256, 256, 0, stream>>>(
        esrc, edst, ea, us, srcP, eaP, ud, sdp, aei, ua, aeid, aoff, nrm, lbl, ul, lnid);

    // NNConv (edge v11 verbatim + separate streaming reduce)
    const int GT = N_ATOMS / NTILE;               // 6250
    const int GF = (N_ATOMS * HD + 255) / 256;    // 7813
    nnconv_edge11<DIN0, 2, true ><<<GT, 256, 0, stream>>>(x,  eaP, srcP, sdp, soff, Mb1, b1, msg, selfm);
    nnconv_reduce2<<<GF, 256, 0, stream>>>(selfm, doff, msg, hA);
    nnconv_edge11<HD,   1, false><<<GT, 256, 0, stream>>>(hA, eaP, srcP, sdp, soff, Mb2, b2, msg, selfm);
    nnconv_reduce2<<<GF, 256, 0, stream>>>(selfm, doff, msg, hB);
    nnconv_edge11<HD,   1, false><<<GT, 256, 0, stream>>>(hB, eaP, srcP, sdp, soff, Mb3, b3, msg, selfm);
    nnconv_reduce2<<<GF, 256, 0, stream>>>(selfm, doff, msg, hA);
    aa_gather<<<(N_AMINO * HD + 255) / 256, 256, 0, stream>>>(hA, loff, lnid, aa);

    // ARMA: gather/GEMM commuted; fused l0 (gather in LDS, 3 stacks); lt loop.
    const size_t KH = (size_t)N_AMINO * HA;
    arma_l0f<<<160, 256, 0, stream>>>(aa, aoff, aeid, aei, nrm, Wp, abi, OA, KH);
    for (int t = 1; t < TL; ++t) {
        const u16* Oin  = (t & 1) ? OA : OB;
        u16*       Oout = (t & 1) ? OB : OA;
        arma_lt<<<dim3(160, KS), 256, 0, stream>>>(
            Oin, Wp + WP0_ELEMS + (size_t)((t - 1) * KS) * 20480,
            abi + (size_t)t * KS * HA, aa, aoff, aeid, aei, nrm, Oout, KH);
    }
    // TL=7: final output (t=6, even) lands in OA.
    head2<<<NGRAPH, 256, 0, stream>>>(OA, KH, bat, l1w, l1b, l2w, l2b,
                                      l3w, l3b, l4w, l4b, outp);
}

// Round 16
// 468.163 us; speedup vs baseline: 1.1525x; 1.0575x over previous
//
#include <hip/hip_runtime.h>

#define N_ATOMS 100000
#define E_ATOMS 200000
#define N_AMINO 10240
#define E_AMINO 20480
#define NGRAPH 512
#define DIN0 40
#define D_E 11
#define HD 20
#define D_AA 8
#define HA 128
#define KS 3
#define TL 7
#define F1 256
#define F2 128
#define F3 64
#define NTILE 16  // nodes per edge-kernel tile (100000 % 16 == 0)
#define ECAP 64   // staged edges per chunk (mean 32/tile; loop handles overflow)
#define EAW 12    // eaP row (u16): 11 attrs + 1.0 pad; 24 B, u32-aligned

typedef unsigned short u16;
typedef unsigned int u32;
typedef __attribute__((ext_vector_type(8))) short short8;
typedef __attribute__((ext_vector_type(4))) float f32x4;

__device__ __forceinline__ float b2f(u16 u) {
    union { u32 i; float f; } v; v.i = ((u32)u) << 16; return v.f;
}
__device__ __forceinline__ u16 f2b(float f) {
    union { float f; u32 i; } v; v.f = f;
    u32 x = v.i;
    return (u16)((x + (((x >> 16) & 1u) + 0x7fffu)) >> 16);
}

// ---------------------------------------------------------------------------
// k_prep: merged prep + ARMA weight pack.
// Part A: Mb matrices in MFMA B-fragment order (bf16; 272 padded cols =
// W(220)|edge-bias(20)|root(20)|0(12), K padded to 32*KB) + aa feature cols
// + zero CSR counts.  Part B: ARMA weight pack (Wp).
#define MB1_ELEMS 17408   // DIN=40 -> KB=2, 2*8704
#define MB2_ELEMS 8704    // DIN=20 -> KB=1
#define PREP0_N (MB1_ELEMS + 2 * MB2_ELEMS + N_AMINO * D_AA + 2 * N_ATOMS + 2 * N_AMINO)
#define WP0_ELEMS (KS * 8192)
#define WP1_ELEMS (6 * KS * 20480)
#define PREP_N (PREP0_N + WP0_ELEMS + WP1_ELEMS)
__global__ __launch_bounds__(256) void k_prep(
    const float* __restrict__ w1, const float* __restrict__ nb1, const float* __restrict__ r1,
    const float* __restrict__ w2, const float* __restrict__ nb2, const float* __restrict__ r2,
    const float* __restrict__ w3, const float* __restrict__ nb3, const float* __restrict__ r3,
    u16* __restrict__ Mb1, u16* __restrict__ Mb2, u16* __restrict__ Mb3,
    const float* __restrict__ af, float* __restrict__ aa,
    int* __restrict__ cs, int* __restrict__ cd,
    int* __restrict__ ca, int* __restrict__ cl,
    const float* __restrict__ ai, const float* __restrict__ aw,
    const float* __restrict__ arw, u16* __restrict__ Wp) {
    int t = blockIdx.x * 256 + threadIdx.x;
    if (t < MB1_ELEMS) {
        int kb = t / 8704, rem = t % 8704;
        int c = rem >> 5, qj = rem & 31;
        int krow = kb * 32 + qj;
        float v = 0.f;
        if (krow < DIN0) {
            if (c < 220)      v = w1[(c / 20) * 800 + krow * 20 + (c % 20)];
            else if (c < 240) v = nb1[krow * 20 + (c - 220)];
            else if (c < 260) v = r1[krow * 20 + (c - 240)];
        }
        Mb1[t] = f2b(v);
    } else if (t < MB1_ELEMS + MB2_ELEMS) {
        int tt = t - MB1_ELEMS;
        int c = tt >> 5, qj = tt & 31;
        float v = 0.f;
        if (qj < HD) {
            if (c < 220)      v = w2[(c / 20) * 400 + qj * 20 + (c % 20)];
            else if (c < 240) v = nb2[qj * 20 + (c - 220)];
            else if (c < 260) v = r2[qj * 20 + (c - 240)];
        }
        Mb2[tt] = f2b(v);
    } else if (t < MB1_ELEMS + 2 * MB2_ELEMS) {
        int tt = t - MB1_ELEMS - MB2_ELEMS;
        int c = tt >> 5, qj = tt & 31;
        float v = 0.f;
        if (qj < HD) {
            if (c < 220)      v = w3[(c / 20) * 400 + qj * 20 + (c % 20)];
            else if (c < 240) v = nb3[qj * 20 + (c - 220)];
            else if (c < 260) v = r3[qj * 20 + (c - 240)];
        }
        Mb3[tt] = f2b(v);
    } else if (t < MB1_ELEMS + 2 * MB2_ELEMS + N_AMINO * D_AA) {
        int idx = t - MB1_ELEMS - 2 * MB2_ELEMS, m = idx / D_AA, j = idx % D_AA;
        aa[m * 28 + HD + j] = af[idx];
    } else if (t < PREP0_N) {
        int z = t - MB1_ELEMS - 2 * MB2_ELEMS - N_AMINO * D_AA;
        if (z < N_ATOMS) cs[z] = 0;
        else if (z < 2 * N_ATOMS) cd[z - N_ATOMS] = 0;
        else if (z < 2 * N_ATOMS + N_AMINO) ca[z - 2 * N_ATOMS] = 0;
        else if (z < 2 * N_ATOMS + 2 * N_AMINO) cl[z - 2 * N_ATOMS - N_AMINO] = 0;
    } else {
        int g = t - PREP0_N;
        if (g < WP0_ELEMS) {
            int k = g / 8192, r = g % 8192;
            int kb = r >> 12, rem = r & 4095;
            int c = rem >> 5, qj = rem & 31;
            int krow = kb * 32 + qj;
            float v = 0.f;
            if (krow < 28)      v = ai[((size_t)k * 28 + krow) * HA + c];
            else if (krow < 56) v = arw[((size_t)k * 28 + (krow - 28)) * HA + c];
            Wp[g] = f2b(v);
        } else if (g < WP0_ELEMS + WP1_ELEMS) {
            int gg = g - WP0_ELEMS;
            int mat = gg / 20480, r = gg % 20480;
            int kb = r / 4096, rem = r & 4095;
            int c = rem >> 5, qj = rem & 31;
            int krow = kb * 32 + qj;
            int tm1 = mat / KS, k = mat % KS;
            float v = 0.f;
            if (krow < 128)      v = aw[((size_t)mat * 128 + krow) * HA + c];
            else if (krow < 156) v = arw[(((size_t)(tm1 + 1) * KS + k) * 28 + (krow - 128)) * HA + c];
            Wp[g] = f2b(v);
        }
    }
}

// ---------------------------------------------------------------------------
#define NBS 98
#define NBA 10

__global__ __launch_bounds__(256) void k_csr_count(
    const int* __restrict__ esrc, const int* __restrict__ edst,
    const int* __restrict__ adst, const int* __restrict__ lbl,
    int* __restrict__ cs, int* __restrict__ cd,
    int* __restrict__ ca, int* __restrict__ cl) {
    int t = blockIdx.x * 256 + threadIdx.x;
    if (t < E_ATOMS) atomicAdd(cs + esrc[t], 1);
    else if (t < 2 * E_ATOMS) atomicAdd(cd + edst[t - E_ATOMS], 1);
    else if (t < 2 * E_ATOMS + E_AMINO) atomicAdd(ca + adst[t - 2 * E_ATOMS], 1);
    else if (t < 2 * E_ATOMS + E_AMINO + N_ATOMS) atomicAdd(cl + lbl[t - 2 * E_ATOMS - E_AMINO], 1);
}
__device__ __forceinline__ void seg_decode(int bx, int* blk, int* n, int* which) {
    if (bx < NBS)            { *which = 0; *blk = bx;             *n = N_ATOMS; }
    else if (bx < 2 * NBS)   { *which = 1; *blk = bx - NBS;       *n = N_ATOMS; }
    else if (bx < 2 * NBS + NBA) { *which = 2; *blk = bx - 2 * NBS; *n = N_AMINO; }
    else                     { *which = 3; *blk = bx - 2 * NBS - NBA; *n = N_AMINO; }
}
__global__ __launch_bounds__(256) void k_scan1(
    const int* __restrict__ cs, int* __restrict__ soff,
    const int* __restrict__ cd, int* __restrict__ doff,
    const int* __restrict__ ca, int* __restrict__ aoff,
    const int* __restrict__ cl, int* __restrict__ loff,
    int* __restrict__ bsum) {
    int blk, n, which;
    seg_decode(blockIdx.x, &blk, &n, &which);
    const int* c = which == 0 ? cs : which == 1 ? cd : which == 2 ? ca : cl;
    int* o = which == 0 ? soff : which == 1 ? doff : which == 2 ? aoff : loff;
    int tx = threadIdx.x, lane = tx & 63, w = tx >> 6;
    int i0 = blk * 1024 + tx * 4;
    int v[4];
#pragma unroll
    for (int q = 0; q < 4; ++q) v[q] = (i0 + q < n) ? c[i0 + q] : 0;
    int s = v[0] + v[1] + v[2] + v[3];
    int inc = s;
#pragma unroll
    for (int d = 1; d < 64; d <<= 1) {
        int u = __shfl_up(inc, d, 64);
        if (lane >= d) inc += u;
    }
    __shared__ int wsum[4];
    if (lane == 63) wsum[w] = inc;
    __syncthreads();
    int wo = 0;
    for (int i = 0; i < w; ++i) wo += wsum[i];
    int run = wo + inc - s;
#pragma unroll
    for (int q = 0; q < 4; ++q) {
        if (i0 + q < n) o[i0 + q] = run;
        run += v[q];
    }
    if (tx == 255) bsum[blockIdx.x] = wo + inc;
}
__global__ __launch_bounds__(128) void k_scan2(
    int* __restrict__ bsum, int* __restrict__ soff, int* __restrict__ doff,
    int* __restrict__ aoff, int* __restrict__ loff) {
    int bx = blockIdx.x;
    int nb   = (bx < 2) ? NBS : NBA;
    int base = (bx == 0) ? 0 : (bx == 1) ? NBS : (bx == 2) ? 2 * NBS : 2 * NBS + NBA;
    int* b = bsum + base;
    int tx = threadIdx.x, lane = tx & 63;
    int v = (tx < nb) ? b[tx] : 0;
    int inc = v;
#pragma unroll
    for (int d = 1; d < 64; d <<= 1) {
        int u = __shfl_up(inc, d, 64);
        if (lane >= d) inc += u;
    }
    __shared__ int w0;
    if (tx == 63) w0 = inc;
    __syncthreads();
    int excl = inc - v + ((tx >= 64) ? w0 : 0);
    if (tx < nb) b[tx] = excl;
    if (tx == nb - 1) {
        int tot = excl + v;
        if (bx == 0) soff[N_ATOMS] = tot;
        else if (bx == 1) doff[N_ATOMS] = tot;
        else if (bx == 2) aoff[N_AMINO] = tot;
        else loff[N_AMINO] = tot;
    }
}
__global__ __launch_bounds__(256) void k_scan3(
    int* __restrict__ soff, int* __restrict__ doff,
    int* __restrict__ aoff, int* __restrict__ loff,
    const int* __restrict__ bsum,
    int* __restrict__ us, int* __restrict__ ud,
    int* __restrict__ ua, int* __restrict__ ul) {
    int blk, n, which;
    seg_decode(blockIdx.x, &blk, &n, &which);
    int* o = which == 0 ? soff : which == 1 ? doff : which == 2 ? aoff : loff;
    int* cu = which == 0 ? us : which == 1 ? ud : which == 2 ? ua : ul;
    int add = bsum[blockIdx.x];
    int i0 = blk * 1024 + threadIdx.x * 4;
#pragma unroll
    for (int q = 0; q < 4; ++q)
        if (i0 + q < n) { int val = o[i0 + q] + add; o[i0 + q] = val; cu[i0 + q] = val; }
}
// fill: src slots -> srcP/eaP(bf16 x11 + 1.0 pad) + sdp (src-slot -> dst-pos),
// amino eids+nrm, label->node
__global__ __launch_bounds__(256) void k_csr_fill(
    const int* __restrict__ esrc, const int* __restrict__ edst,
    const float* __restrict__ ea,
    int* __restrict__ us, int* __restrict__ srcP, u16* __restrict__ eaP,
    int* __restrict__ ud, int* __restrict__ sdp,
    const int* __restrict__ aei, int* __restrict__ ua, int* __restrict__ aeid,
    const int* __restrict__ aoff, float* __restrict__ nrm,
    const int* __restrict__ lbl, int* __restrict__ ul, int* __restrict__ lnid) {
    int t = blockIdx.x * 256 + threadIdx.x;
    if (t < E_ATOMS) {
        int jj = atomicAdd(us + esrc[t], 1);
        srcP[jj] = esrc[t];
        const float* e0 = ea + (size_t)t * D_E;
        u16* e1 = eaP + (size_t)jj * EAW;
#pragma unroll
        for (int k = 0; k < D_E; ++k) e1[k] = f2b(e0[k]);
        e1[D_E] = f2b(1.0f);   // pad = 1.0: folds edge-MLP bias into the 12-dot
        sdp[jj] = atomicAdd(ud + edst[t], 1);   // dst-CSR position for this edge
    } else if (t < E_ATOMS + E_AMINO) {
        int e = t - E_ATOMS;
        int p = atomicAdd(ua + aei[E_AMINO + e], 1);
        aeid[p] = e;
    } else if (t < E_ATOMS + 2 * E_AMINO) {
        int e = t - E_ATOMS - E_AMINO;
        int s = aei[e], d = aei[E_AMINO + e];
        int ds = aoff[s + 1] - aoff[s], dd = aoff[d + 1] - aoff[d];
        float a = ds > 0 ? rsqrtf((float)ds) : 0.f;
        float b = dd > 0 ? rsqrtf((float)dd) : 0.f;
        nrm[e] = a * b;
    } else if (t < E_ATOMS + 2 * E_AMINO + N_ATOMS) {
        int n = t - E_ATOMS - 2 * E_AMINO;
        int p = atomicAdd(ul + lbl[n], 1);
        lnid[p] = n;
    }
}

// ---------------------------------------------------------------------------
// NNConv edge v11 (the 469-us build's kernel, verbatim): MFMA phase-1 over 17
// col-tiles (240 msg-dot cols -> packed y3; 20 root cols -> selfm = x@root +
// bias). Phase 2: 20 lanes/edge, scalar u16 store, dst-ordered msg.
// R12/R15 lesson: the 2-output u32 phase-2 variant regressed 44 -> 61.5 us.
template <int DIN, int KB, bool RAW>
__global__ __launch_bounds__(256, 6) void nnconv_edge11(
    const void* __restrict__ xin, const u16* __restrict__ eaP,
    const int* __restrict__ srcP, const int* __restrict__ sdp,
    const int* __restrict__ soff, const u16* __restrict__ Mb,
    const float* __restrict__ bnn, u16* __restrict__ msg,
    u16* __restrict__ selfm) {
    constexpr int KPAD = KB * 32;
    __shared__ __align__(16) float y3[NTILE * 240];
    __shared__ __align__(16) u16 As[NTILE * KPAD];
    __shared__ __align__(16) float eaS[ECAP * 12];
    __shared__ int srcS[ECAP];
    __shared__ int sdpS[ECAP];
    int tx = threadIdx.x;
    int n0 = blockIdx.x * NTILE;         // N_ATOMS % NTILE == 0
    int j0 = soff[n0], j1 = soff[n0 + NTILE];
    // stage X as bf16 A-fragments (node-major rows, zero-pad k >= DIN)
    for (int i = tx; i < NTILE * KPAD; i += 256) {
        int node = i / KPAD, k = i % KPAD;
        u16 v = 0;
        if (k < DIN)
            v = RAW ? f2b(((const float*)xin)[(size_t)(n0 + node) * DIN + k])
                    : ((const u16*)xin)[(size_t)(n0 + node) * DIN + k];
        As[i] = v;
    }
    // stage phase-2 chunk 0
    {
        int cn0 = j1 - j0; if (cn0 > ECAP) cn0 = ECAP;
        for (int i = tx; i < cn0; i += 256) {
            srcS[i] = srcP[j0 + i] - n0;
            sdpS[i] = sdp[j0 + i];
        }
        const u32* eg = (const u32*)(eaP + (size_t)j0 * EAW);
        for (int i = tx; i < cn0 * 6; i += 256) {
            u32 pv = eg[i];
            eaS[2 * i]     = b2f((u16)(pv & 0xffff));
            eaS[2 * i + 1] = b2f((u16)(pv >> 16));
        }
    }
    __syncthreads();
    // phase 1: MFMA over 17 col-tiles; wave handles ct = wave, wave+4, ...
    {
        int wave = tx >> 6, lane = tx & 63;
        int m = lane & 15, q = lane >> 4;
        short8 aF[KB];
#pragma unroll
        for (int kb = 0; kb < KB; ++kb)
            aF[kb] = *(const short8*)&As[m * KPAD + kb * 32 + q * 8];
        for (int ct = wave; ct < 17; ct += 4) {
            int c0 = ct * 16;
            f32x4 acc = {0.f, 0.f, 0.f, 0.f};
#pragma unroll
            for (int kb = 0; kb < KB; ++kb) {
                short8 bF = *(const short8*)(Mb + (size_t)kb * 8704 + (size_t)(c0 + m) * 32 + q * 8);
                acc = __builtin_amdgcn_mfma_f32_16x16x32_bf16(aF[kb], bF, acc, 0, 0, 0);
            }
            int c = c0 + m;
            if (c < 240) {
                int slot = (c < 220) ? (c % 20) * 12 + c / 20 : (c - 220) * 12 + 11;
#pragma unroll
                for (int r = 0; r < 4; ++r)
                    y3[(q * 4 + r) * 240 + slot] = acc[r];
            } else if (c < 260) {
                float bv = bnn[c - 240];
#pragma unroll
                for (int r = 0; r < 4; ++r)
                    selfm[(size_t)(n0 + q * 4 + r) * HD + (c - 240)] = f2b(acc[r] + bv);
            }
        }
    }
    __syncthreads();
    // phase 2: LDS-only; task p = (edge e, out o); 12-dot; msg in dst order
    int c0 = j0;
    while (true) {
        int cn = j1 - c0; if (cn > ECAP) cn = ECAP;
        for (int p = tx; p < cn * 20; p += 256) {
            int e = p / 20, o = p - e * 20;
            const float4* ev = (const float4*)&eaS[e * 12];
            const float4* yr = (const float4*)&y3[srcS[e] * 240 + o * 12];
            float4 e0 = ev[0], e1 = ev[1], e2 = ev[2];
            float4 q0 = yr[0], q1 = yr[1], q2 = yr[2];
            float mv = e0.x * q0.x + e0.y * q0.y + e0.z * q0.z + e0.w * q0.w
                     + e1.x * q1.x + e1.y * q1.y + e1.z * q1.z + e1.w * q1.w
                     + e2.x * q2.x + e2.y * q2.y + e2.z * q2.z + e2.w * q2.w;
            msg[(size_t)sdpS[e] * 20 + o] = f2b(mv);
        }
        c0 += cn;
        if (c0 >= j1) break;
        // rare: tile had >ECAP edges — restage next chunk
        __syncthreads();
        int cm = j1 - c0; if (cm > ECAP) cm = ECAP;
        for (int i = tx; i < cm; i += 256) {
            srcS[i] = srcP[c0 + i] - n0;
            sdpS[i] = sdp[c0 + i];
        }
        const u32* eg = (const u32*)(eaP + (size_t)c0 * EAW);
        for (int i = tx; i < cm * 6; i += 256) {
            u32 pv = eg[i];
            eaS[2 * i]     = b2f((u16)(pv & 0xffff));
            eaS[2 * i + 1] = b2f((u16)(pv >> 16));
        }
        __syncthreads();
    }
}

// NNConv reduce v2: pure streaming. h = relu(selfm + sum of contiguous
// dst-ordered msg rows). No x, no root, no indirection.
__global__ __launch_bounds__(256) void nnconv_reduce2(
    const u16* __restrict__ selfm, const int* __restrict__ doff,
    const u16* __restrict__ msg, u16* __restrict__ hout) {
    int t = blockIdx.x * 256 + threadIdx.x;
    if (t >= N_ATOMS * HD) return;
    int n = t / HD, o = t - n * HD;
    float acc = b2f(selfm[t]);
    int j1 = doff[n + 1];
    for (int j = doff[n]; j < j1; ++j)
        acc += b2f(msg[(size_t)j * HD + o]);
    hout[t] = f2b(fmaxf(acc, 0.f));
}

// aa gather: label-CSR segmented sum of h3
__global__ __launch_bounds__(256) void aa_gather(
    const u16* __restrict__ h3, const int* __restrict__ loff,
    const int* __restrict__ lnid, float* __restrict__ aa) {
    int t = blockIdx.x * 256 + threadIdx.x;
    if (t >= N_AMINO * HD) return;
    int m = t / HD, o = t % HD;
    float s = 0.f;
    int j1 = loff[m + 1];
    for (int j = loff[m]; j < j1; ++j)
        s += b2f(h3[(size_t)lnid[j] * HD + o]);
    aa[m * 28 + o] = s;
}

// ---------------------------------------------------------------------------
// k_gaa: build A0[10240][64] bf16 = [gather(aa)(28) | aa(28) | 0(8)].
// (R10 proven pair restored: 2560-block gather + 480-block MFMA beats the
// 160-block fused arma_l0f, which idled 60% of CUs — R15 A/B.)
__global__ __launch_bounds__(256) void k_gaa(
    const float* __restrict__ aa, const int* __restrict__ aoff,
    const int* __restrict__ aeid, const int* __restrict__ aei,
    const float* __restrict__ nrm, u16* __restrict__ A0) {
    int t = blockIdx.x * 256 + threadIdx.x;
    if (t >= N_AMINO * 64) return;
    int n = t >> 6, c = t & 63;
    float v = 0.f;
    if (c < 28) {
        int j1 = aoff[n + 1];
        for (int jj = aoff[n]; jj < j1; ++jj) {
            int e = aeid[jj], s = aei[e];
            v += nrm[e] * aa[(size_t)s * 28 + c];
        }
    } else if (c < 56) {
        v = aa[(size_t)n * 28 + (c - 28)];
    }
    A0[t] = f2b(v);
}

// ARMA layer 0: O = relu(A0 @ [init;root0] + bias). Pure MFMA, A0 global.
__global__ __launch_bounds__(256) void arma_l0(
    const u16* __restrict__ A0, const u16* __restrict__ Wp0,
    const float* __restrict__ abi, u16* __restrict__ O, size_t kstride) {
    int wave = threadIdx.x >> 6, lane = threadIdx.x & 63;
    int k = blockIdx.y;
    const u16* W = Wp0 + (size_t)k * 8192;
    u16* Ok = O + (size_t)k * kstride;
    const float* bk = abi + (size_t)k * HA;   // abi[t=0][k][:]
    int n0 = (blockIdx.x * 4 + wave) * 16;
    int m = lane & 15, q = lane >> 4;
    short8 aF[2];
#pragma unroll
    for (int kb = 0; kb < 2; ++kb)
        aF[kb] = *(const short8*)(A0 + (size_t)(n0 + m) * 64 + kb * 32 + q * 8);
#pragma unroll
    for (int ct = 0; ct < 8; ++ct) {
        int c0 = ct * 16;
        float b = bk[c0 + m];
        f32x4 acc = {b, b, b, b};
#pragma unroll
        for (int kb = 0; kb < 2; ++kb) {
            short8 bF = *(const short8*)(W + (size_t)((kb * 128 + c0 + m) * 32 + q * 8));
            acc = __builtin_amdgcn_mfma_f32_16x16x32_bf16(aF[kb], bF, acc, 0, 0, 0);
        }
#pragma unroll
        for (int r = 0; r < 4; ++r)
            Ok[(size_t)(n0 + q * 4 + r) * HA + c0 + m] = f2b(fmaxf(acc[r], 0.f));
    }
}

// ARMA layer t>=1 fused: gather G=sum nrm*Oprev[src] into LDS (+aa cols),
// then O = relu([G|aa] @ [W;root] + bias) via MFMA (K=160). 64-node tiles.
__global__ __launch_bounds__(256) void arma_lt(
    const u16* __restrict__ Oprev, const u16* __restrict__ Wm,
    const float* __restrict__ abit, const float* __restrict__ aa,
    const int* __restrict__ aoff, const int* __restrict__ aeid,
    const int* __restrict__ aei, const float* __restrict__ nrm,
    u16* __restrict__ Onext, size_t kstride) {
    __shared__ __align__(16) u16 As[64 * 160];
    int tx = threadIdx.x;
    int k = blockIdx.y;
    int n0b = blockIdx.x * 64;
    const u16* Op = Oprev + (size_t)k * kstride;
    const u16* W  = Wm + (size_t)k * 20480;   // per-stack weight offset
    // gather phase: 1024 tasks = 64 nodes x 16 col-blocks (8 bf16 each)
    for (int i = tx; i < 1024; i += 256) {
        int nl = i >> 4, cb = i & 15;
        int n = n0b + nl;
        int j1 = aoff[n + 1];
        float a0 = 0.f, a1 = 0.f, a2 = 0.f, a3 = 0.f;
        float a4 = 0.f, a5 = 0.f, a6 = 0.f, a7 = 0.f;
        for (int jj = aoff[n]; jj < j1; ++jj) {
            int e = aeid[jj], s = aei[e];
            float nm = nrm[e];
            uint4 hv = *(const uint4*)(Op + (size_t)s * HA + cb * 8);
            a0 += nm * b2f((u16)(hv.x & 0xffff));
            a1 += nm * b2f((u16)(hv.x >> 16));
            a2 += nm * b2f((u16)(hv.y & 0xffff));
            a3 += nm * b2f((u16)(hv.y >> 16));
            a4 += nm * b2f((u16)(hv.z & 0xffff));
            a5 += nm * b2f((u16)(hv.z >> 16));
            a6 += nm * b2f((u16)(hv.w & 0xffff));
            a7 += nm * b2f((u16)(hv.w >> 16));
        }
        uint4 pk;
        pk.x = (u32)f2b(a0) | ((u32)f2b(a1) << 16);
        pk.y = (u32)f2b(a2) | ((u32)f2b(a3) << 16);
        pk.z = (u32)f2b(a4) | ((u32)f2b(a5) << 16);
        pk.w = (u32)f2b(a6) | ((u32)f2b(a7) << 16);
        *(uint4*)&As[nl * 160 + cb * 8] = pk;
    }
    // aa cols 128..159: 256 tasks = 64 nodes x 4 col-blocks
    {
        int nl = tx >> 2, cb = tx & 3;
        int n = n0b + nl;
        float av[8];
#pragma unroll
        for (int j = 0; j < 8; ++j) {
            int c = cb * 8 + j;
            av[j] = (c < 28) ? aa[(size_t)n * 28 + c] : 0.f;
        }
        uint4 pk;
        pk.x = (u32)f2b(av[0]) | ((u32)f2b(av[1]) << 16);
        pk.y = (u32)f2b(av[2]) | ((u32)f2b(av[3]) << 16);
        pk.z = (u32)f2b(av[4]) | ((u32)f2b(av[5]) << 16);
        pk.w = (u32)f2b(av[6]) | ((u32)f2b(av[7]) << 16);
        *(uint4*)&As[nl * 160 + 128 + cb * 8] = pk;
    }
    __syncthreads();
    // MFMA phase: wave w -> rows n0b + w*16 .. +16, K = 160 (5 kb-blocks)
    int wave = tx >> 6, lane = tx & 63;
    int m = lane & 15, q = lane >> 4;
    int wl = wave * 16 + m;
    short8 aF[5];
#pragma unroll
    for (int kb = 0; kb < 5; ++kb)
        aF[kb] = *(const short8*)&As[wl * 160 + kb * 32 + q * 8];
    int n0 = n0b + wave * 16;
    u16* On = Onext + (size_t)k * kstride;
    const float* bk = abit + (size_t)k * HA;
#pragma unroll
    for (int ct = 0; ct < 8; ++ct) {
        int c0 = ct * 16;
        float b = bk[c0 + m];
        f32x4 acc = {b, b, b, b};
#pragma unroll
        for (int kb = 0; kb < 5; ++kb) {
            short8 bF = *(const short8*)(W + (size_t)((kb * 128 + c0 + m) * 32 + q * 8));
            acc = __builtin_amdgcn_mfma_f32_16x16x32_bf16(aF[kb], bF, acc, 0, 0, 0);
        }
#pragma unroll
        for (int r = 0; r < 4; ++r)
            On[(size_t)(n0 + q * 4 + r) * HA + c0 + m] = f2b(fmaxf(acc[r], 0.f));
    }
}

// ---------------------------------------------------------------------------
// head2: fused readout (sorted amino_batch segmented sum over bf16 O) + MLP.
__global__ __launch_bounds__(256) void head2(
    const u16* __restrict__ O, size_t kstride, const int* __restrict__ bat,
    const float* __restrict__ l1w, const float* __restrict__ l1b,
    const float* __restrict__ l2w, const float* __restrict__ l2b,
    const float* __restrict__ l3w, const float* __restrict__ l3b,
    const float* __restrict__ l4w, const float* __restrict__ l4b,
    float* __restrict__ outp) {
    __shared__ float sg[HA], sp1[F1], sp2[F2], sp3[F3];
    int b = blockIdx.x, tx = threadIdx.x;
    int lo = 0, hi = N_AMINO;
    while (lo < hi) { int mid = (lo + hi) >> 1; if (bat[mid] < b) lo = mid + 1; else hi = mid; }
    int s = lo;
    lo = 0; hi = N_AMINO;
    while (lo < hi) { int mid = (lo + hi) >> 1; if (bat[mid] < b + 1) lo = mid + 1; else hi = mid; }
    int e = lo;
    if (tx < HA) {
        float acc = 0.f;
        for (int n = s; n < e; ++n)
            acc += b2f(O[(size_t)n * HA + tx]) + b2f(O[kstride + (size_t)n * HA + tx])
                 + b2f(O[2 * kstride + (size_t)n * HA + tx]);
        sg[tx] = acc * (1.f / 3.f);
    }
    __syncthreads();
    {   float acc = l1b[tx];
        for (int f = 0; f < HA; ++f) acc += sg[f] * l1w[f * F1 + tx];
        sp1[tx] = fmaxf(acc, 0.f); }
    __syncthreads();
    if (tx < F2) {
        float acc = l2b[tx];
        for (int f = 0; f < F1; ++f) acc += sp1[f] * l2w[f * F2 + tx];
        sp2[tx] = fmaxf(acc, 0.f); }
    __syncthreads();
    if (tx < F3) {
        float acc = l3b[tx];
        for (int f = 0; f < F2; ++f) acc += sp2[f] * l3w[f * F3 + tx];
        sp3[tx] = fmaxf(acc, 0.f); }
    __syncthreads();
    if (tx < 64) {
        float p = sp3[tx] * l4w[tx];
        for (int off = 32; off > 0; off >>= 1) p += __shfl_down(p, off, 64);
        if (tx == 0) outp[b] = p + l4b[0];
    }
}

// ---------------------------------------------------------------------------
// Workspace (<= 34,348,288 B, proven available).
#define OFF_M1    ((size_t)0)        // Mb1 bf16 34,816 B
#define OFF_M2    ((size_t)38400)    // Mb2 bf16 17,408 B
#define OFF_M3    ((size_t)57600)    // Mb3 bf16 17,408 B (ends 75,008)
#define OFF_AOFF  ((size_t)76800)
#define OFF_AEID  ((size_t)118016)
#define OFF_NRM   ((size_t)199936)
#define OFF_AA    ((size_t)281856)
#define OFF_HA    ((size_t)2891008)   // 4,000,000 -> 6,891,008
#define OFF_HB    ((size_t)6891008)   // 4,000,000 -> 10,891,008
#define OFF_MSG   ((size_t)10891008)  // 8,000,000 -> 18,891,008
#define OFF_SOFF  ((size_t)18891008)
#define OFF_DOFF  ((size_t)19291136)
#define OFF_DSLOT ((size_t)19691264)  // sdp: src-slot -> dst-pos
#define OFF_LOFF  ((size_t)20491264)
#define OFF_LNID  ((size_t)20532480)
#define OFF_CS    ((size_t)20932480)
#define OFF_CD    ((size_t)21332480)
#define OFF_CA    ((size_t)21732480)
#define OFF_CL    ((size_t)21773440)
#define OFF_US    ((size_t)21814400)
#define OFF_UD    ((size_t)22214400)
#define OFF_UA    ((size_t)22614400)
#define OFF_UL    ((size_t)22655360)
#define OFF_BSUM  ((size_t)22696320)
#define OFF_EAP   ((size_t)22697216)      // bf16x12 4,800,000 -> 27,497,216
#define OFF_SRCP  ((size_t)27497216)      // 800,000 -> 28,297,216
#define OFF_WP    ((size_t)28297216)      // 786,432 -> 29,083,648
#define OFF_SELFM ((size_t)29083648)      // bf16 4,000,000 -> 33,083,648
// ARMA overlays (NNConv buffers dead by then):
//   OB (odd-layer O): 2,891,008..10,755,328  (over hA/hB)
//   A0: 10,891,008 + 1,310,720 = 12,201,728  (over msg, dead after reduce2 #3)
//   OA (even-layer O): 18,619,648..26,483,968 (over msg tail + eaP)
#define OFF_OB    ((size_t)2891008)
#define OFF_A0    ((size_t)10891008)
#define OFF_OA    ((size_t)18619648)

extern "C" void kernel_launch(void* const* d_in, const int* in_sizes, int n_in,
                              void* d_out, int out_size, void* d_ws, size_t ws_size,
                              hipStream_t stream) {
    (void)in_sizes; (void)n_in; (void)out_size; (void)ws_size;
    const float* x   = (const float*)d_in[0];
    const int*   ei  = (const int*)d_in[1];
    const float* ea  = (const float*)d_in[2];
    const int*   lbl = (const int*)d_in[3];
    const float* af  = (const float*)d_in[4];
    const int*   aei = (const int*)d_in[5];
    const int*   bat = (const int*)d_in[6];
    const float* nn1w = (const float*)d_in[7];  const float* nn1b = (const float*)d_in[8];
    const float* rt1  = (const float*)d_in[9];  const float* b1   = (const float*)d_in[10];
    const float* nn2w = (const float*)d_in[11]; const float* nn2b = (const float*)d_in[12];
    const float* rt2  = (const float*)d_in[13]; const float* b2   = (const float*)d_in[14];
    const float* nn3w = (const float*)d_in[15]; const float* nn3b = (const float*)d_in[16];
    const float* rt3  = (const float*)d_in[17]; const float* b3   = (const float*)d_in[18];
    const float* ai   = (const float*)d_in[19]; const float* aw   = (const float*)d_in[20];
    const float* arw  = (const float*)d_in[21]; const float* abi  = (const float*)d_in[22];
    const float* l1w  = (const float*)d_in[23]; const float* l1b  = (const float*)d_in[24];
    const float* l2w  = (const float*)d_in[25]; const float* l2b  = (const float*)d_in[26];
    const float* l3w  = (const float*)d_in[27]; const float* l3b  = (const float*)d_in[28];
    const float* l4w  = (const float*)d_in[29]; const float* l4b  = (const float*)d_in[30];
    float* outp = (float*)d_out;

    char* ws = (char*)d_ws;
    u16*   Mb1   = (u16*)(ws + OFF_M1);
    u16*   Mb2   = (u16*)(ws + OFF_M2);
    u16*   Mb3   = (u16*)(ws + OFF_M3);
    int*   aoff  = (int*)(ws + OFF_AOFF);
    int*   aeid  = (int*)(ws + OFF_AEID);
    float* nrm   = (float*)(ws + OFF_NRM);
    float* aa    = (float*)(ws + OFF_AA);
    u16*   hA    = (u16*)(ws + OFF_HA);
    u16*   hB    = (u16*)(ws + OFF_HB);
    u16*   msg   = (u16*)(ws + OFF_MSG);
    int*   soff  = (int*)(ws + OFF_SOFF);
    int*   doff  = (int*)(ws + OFF_DOFF);
    int*   sdp   = (int*)(ws + OFF_DSLOT);
    int*   loff  = (int*)(ws + OFF_LOFF);
    int*   lnid  = (int*)(ws + OFF_LNID);
    int*   cs    = (int*)(ws + OFF_CS);
    int*   cd    = (int*)(ws + OFF_CD);
    int*   ca    = (int*)(ws + OFF_CA);
    int*   cl    = (int*)(ws + OFF_CL);
    int*   us    = (int*)(ws + OFF_US);
    int*   ud    = (int*)(ws + OFF_UD);
    int*   ua    = (int*)(ws + OFF_UA);
    int*   ul    = (int*)(ws + OFF_UL);
    int*   bsum  = (int*)(ws + OFF_BSUM);
    u16*   eaP   = (u16*)(ws + OFF_EAP);
    int*   srcP  = (int*)(ws + OFF_SRCP);
    u16*   Wp    = (u16*)(ws + OFF_WP);
    u16*   selfm = (u16*)(ws + OFF_SELFM);
    u16*   A0    = (u16*)(ws + OFF_A0);
    u16*   OA    = (u16*)(ws + OFF_OA);
    u16*   OB    = (u16*)(ws + OFF_OB);

    const int* esrc = ei;
    const int* edst = ei + E_ATOMS;
    const int* adst = aei + E_AMINO;

    // prep (merged prep + weight pack)
    k_prep<<<(PREP_N + 255) / 256, 256, 0, stream>>>(
        nn1w, nn1b, rt1, nn2w, nn2b, rt2, nn3w, nn3b, rt3,
        Mb1, Mb2, Mb3, af, aa, cs, cd, ca, cl, ai, aw, arw, Wp);
    k_csr_count<<<(2 * E_ATOMS + E_AMINO + N_ATOMS + 255) / 256, 256, 0, stream>>>(
        esrc, edst, adst, lbl, cs, cd, ca, cl);
    k_scan1<<<2 * NBS + 2 * NBA, 256, 0, stream>>>(cs, soff, cd, doff, ca, aoff, cl, loff, bsum);
    k_scan2<<<4, 128, 0, stream>>>(bsum, soff, doff, aoff, loff);
    k_scan3<<<2 * NBS + 2 * NBA, 256, 0, stream>>>(soff, doff, aoff, loff, bsum, us, ud, ua, ul);
    k_csr_fill<<<(E_ATOMS + 2 * E_AMINO + N_ATOMS + 255) / 256, 256, 0, stream>>>(
        esrc, edst, ea, us, srcP, eaP, ud, sdp, aei, ua, aeid, aoff, nrm, lbl, ul, lnid);

    // NNConv (edge v11 + separate streaming reduce)
    const int GT = N_ATOMS / NTILE;               // 6250
    const int GF = (N_ATOMS * HD + 255) / 256;    // 7813
    nnconv_edge11<DIN0, 2, true ><<<GT, 256, 0, stream>>>(x,  eaP, srcP, sdp, soff, Mb1, b1, msg, selfm);
    nnconv_reduce2<<<GF, 256, 0, stream>>>(selfm, doff, msg, hA);
    nnconv_edge11<HD,   1, false><<<GT, 256, 0, stream>>>(hA, eaP, srcP, sdp, soff, Mb2, b2, msg, selfm);
    nnconv_reduce2<<<GF, 256, 0, stream>>>(selfm, doff, msg, hB);
    nnconv_edge11<HD,   1, false><<<GT, 256, 0, stream>>>(hB, eaP, srcP, sdp, soff, Mb3, b3, msg, selfm);
    nnconv_reduce2<<<GF, 256, 0, stream>>>(selfm, doff, msg, hA);
    aa_gather<<<(N_AMINO * HD + 255) / 256, 256, 0, stream>>>(hA, loff, lnid, aa);

    // ARMA: gather/GEMM commuted; R10 pair (k_gaa + arma_l0) restored; lt loop.
    const size_t KH = (size_t)N_AMINO * HA;
    k_gaa<<<(N_AMINO * 64 + 255) / 256, 256, 0, stream>>>(aa, aoff, aeid, aei, nrm, A0);
    arma_l0<<<dim3(160, KS), 256, 0, stream>>>(A0, Wp, abi, OA, KH);
    for (int t = 1; t < TL; ++t) {
        const u16* Oin  = (t & 1) ? OA : OB;
        u16*       Oout = (t & 1) ? OB : OA;
        arma_lt<<<dim3(160, KS), 256, 0, stream>>>(
            Oin, Wp + WP0_ELEMS + (size_t)((t - 1) * KS) * 20480,
            abi + (size_t)t * KS * HA, aa, aoff, aeid, aei, nrm, Oout, KH);
    }
    // TL=7: final output (t=6, even) lands in OA.
    head2<<<NGRAPH, 256, 0, stream>>>(OA, KH, bat, l1w, l1b, l2w, l2b,
                                      l3w, l3b, l4w, l4b, outp);
}

// Round 21
// 442.809 us; speedup vs baseline: 1.2185x; 1.0573x over previous
//
#include <hip/hip_runtime.h>

#define N_ATOMS 100000
#define E_ATOMS 200000
#define N_AMINO 10240
#define E_AMINO 20480
#define NGRAPH 512
#define DIN0 40
#define D_E 11
#define HD 20
#define D_AA 8
#define HA 128
#define KS 3
#define TL 7
#define F1 256
#define F2 128
#define F3 64
#define NTILE 16  // nodes per edge-kernel tile (100000 % 16 == 0)
#define ECAP 64   // staged edges per chunk (mean 32/tile; loop handles overflow)
#define EAW 12    // eaP row (u16): 11 attrs + 1.0 pad; 24 B, u32-aligned

typedef unsigned short u16;
typedef unsigned int u32;
typedef __attribute__((ext_vector_type(8))) short short8;
typedef __attribute__((ext_vector_type(4))) float f32x4;

__device__ __forceinline__ float b2f(u16 u) {
    union { u32 i; float f; } v; v.i = ((u32)u) << 16; return v.f;
}
__device__ __forceinline__ u16 f2b(float f) {
    union { float f; u32 i; } v; v.f = f;
    u32 x = v.i;
    return (u16)((x + (((x >> 16) & 1u) + 0x7fffu)) >> 16);
}

// ---------------------------------------------------------------------------
// k_prep: merged prep + ARMA weight pack.
// Part A: Mb matrices in MFMA B-fragment order (bf16; 272 padded cols =
// W(220)|edge-bias(20)|root(20)|0(12), K padded to 32*KB) + aa feature cols
// + zero CSR counts.  Part B: ARMA weight pack (Wp).
#define MB1_ELEMS 17408   // DIN=40 -> KB=2, 2*8704
#define MB2_ELEMS 8704    // DIN=20 -> KB=1
#define PREP0_N (MB1_ELEMS + 2 * MB2_ELEMS + N_AMINO * D_AA + 2 * N_ATOMS + 2 * N_AMINO)
#define WP0_ELEMS (KS * 8192)
#define WP1_ELEMS (6 * KS * 20480)
#define PREP_N (PREP0_N + WP0_ELEMS + WP1_ELEMS)
__global__ __launch_bounds__(256) void k_prep(
    const float* __restrict__ w1, const float* __restrict__ nb1, const float* __restrict__ r1,
    const float* __restrict__ w2, const float* __restrict__ nb2, const float* __restrict__ r2,
    const float* __restrict__ w3, const float* __restrict__ nb3, const float* __restrict__ r3,
    u16* __restrict__ Mb1, u16* __restrict__ Mb2, u16* __restrict__ Mb3,
    const float* __restrict__ af, float* __restrict__ aa,
    int* __restrict__ cs, int* __restrict__ cd,
    int* __restrict__ ca, int* __restrict__ cl,
    const float* __restrict__ ai, const float* __restrict__ aw,
    const float* __restrict__ arw, u16* __restrict__ Wp) {
    int t = blockIdx.x * 256 + threadIdx.x;
    if (t < MB1_ELEMS) {
        int kb = t / 8704, rem = t % 8704;
        int c = rem >> 5, qj = rem & 31;
        int krow = kb * 32 + qj;
        float v = 0.f;
        if (krow < DIN0) {
            if (c < 220)      v = w1[(c / 20) * 800 + krow * 20 + (c % 20)];
            else if (c < 240) v = nb1[krow * 20 + (c - 220)];
            else if (c < 260) v = r1[krow * 20 + (c - 240)];
        }
        Mb1[t] = f2b(v);
    } else if (t < MB1_ELEMS + MB2_ELEMS) {
        int tt = t - MB1_ELEMS;
        int c = tt >> 5, qj = tt & 31;
        float v = 0.f;
        if (qj < HD) {
            if (c < 220)      v = w2[(c / 20) * 400 + qj * 20 + (c % 20)];
            else if (c < 240) v = nb2[qj * 20 + (c - 220)];
            else if (c < 260) v = r2[qj * 20 + (c - 240)];
        }
        Mb2[tt] = f2b(v);
    } else if (t < MB1_ELEMS + 2 * MB2_ELEMS) {
        int tt = t - MB1_ELEMS - MB2_ELEMS;
        int c = tt >> 5, qj = tt & 31;
        float v = 0.f;
        if (qj < HD) {
            if (c < 220)      v = w3[(c / 20) * 400 + qj * 20 + (c % 20)];
            else if (c < 240) v = nb3[qj * 20 + (c - 220)];
            else if (c < 260) v = r3[qj * 20 + (c - 240)];
        }
        Mb3[tt] = f2b(v);
    } else if (t < MB1_ELEMS + 2 * MB2_ELEMS + N_AMINO * D_AA) {
        int idx = t - MB1_ELEMS - 2 * MB2_ELEMS, m = idx / D_AA, j = idx % D_AA;
        aa[m * 28 + HD + j] = af[idx];
    } else if (t < PREP0_N) {
        int z = t - MB1_ELEMS - 2 * MB2_ELEMS - N_AMINO * D_AA;
        if (z < N_ATOMS) cs[z] = 0;
        else if (z < 2 * N_ATOMS) cd[z - N_ATOMS] = 0;
        else if (z < 2 * N_ATOMS + N_AMINO) ca[z - 2 * N_ATOMS] = 0;
        else if (z < 2 * N_ATOMS + 2 * N_AMINO) cl[z - 2 * N_ATOMS - N_AMINO] = 0;
    } else {
        int g = t - PREP0_N;
        if (g < WP0_ELEMS) {
            int k = g / 8192, r = g % 8192;
            int kb = r >> 12, rem = r & 4095;
            int c = rem >> 5, qj = rem & 31;
            int krow = kb * 32 + qj;
            float v = 0.f;
            if (krow < 28)      v = ai[((size_t)k * 28 + krow) * HA + c];
            else if (krow < 56) v = arw[((size_t)k * 28 + (krow - 28)) * HA + c];
            Wp[g] = f2b(v);
        } else if (g < WP0_ELEMS + WP1_ELEMS) {
            int gg = g - WP0_ELEMS;
            int mat = gg / 20480, r = gg % 20480;
            int kb = r / 4096, rem = r & 4095;
            int c = rem >> 5, qj = rem & 31;
            int krow = kb * 32 + qj;
            int tm1 = mat / KS, k = mat % KS;
            float v = 0.f;
            if (krow < 128)      v = aw[((size_t)mat * 128 + krow) * HA + c];
            else if (krow < 156) v = arw[(((size_t)(tm1 + 1) * KS + k) * 28 + (krow - 128)) * HA + c];
            Wp[g] = f2b(v);
        }
    }
}

// ---------------------------------------------------------------------------
#define NBS 98
#define NBA 10

__global__ __launch_bounds__(256) void k_csr_count(
    const int* __restrict__ esrc, const int* __restrict__ edst,
    const int* __restrict__ adst, const int* __restrict__ lbl,
    int* __restrict__ cs, int* __restrict__ cd,
    int* __restrict__ ca, int* __restrict__ cl) {
    int t = blockIdx.x * 256 + threadIdx.x;
    if (t < E_ATOMS) atomicAdd(cs + esrc[t], 1);
    else if (t < 2 * E_ATOMS) atomicAdd(cd + edst[t - E_ATOMS], 1);
    else if (t < 2 * E_ATOMS + E_AMINO) atomicAdd(ca + adst[t - 2 * E_ATOMS], 1);
    else if (t < 2 * E_ATOMS + E_AMINO + N_ATOMS) atomicAdd(cl + lbl[t - 2 * E_ATOMS - E_AMINO], 1);
}
__device__ __forceinline__ void seg_decode(int bx, int* blk, int* n, int* which) {
    if (bx < NBS)            { *which = 0; *blk = bx;             *n = N_ATOMS; }
    else if (bx < 2 * NBS)   { *which = 1; *blk = bx - NBS;       *n = N_ATOMS; }
    else if (bx < 2 * NBS + NBA) { *which = 2; *blk = bx - 2 * NBS; *n = N_AMINO; }
    else                     { *which = 3; *blk = bx - 2 * NBS - NBA; *n = N_AMINO; }
}
__global__ __launch_bounds__(256) void k_scan1(
    const int* __restrict__ cs, int* __restrict__ soff,
    const int* __restrict__ cd, int* __restrict__ doff,
    const int* __restrict__ ca, int* __restrict__ aoff,
    const int* __restrict__ cl, int* __restrict__ loff,
    int* __restrict__ bsum) {
    int blk, n, which;
    seg_decode(blockIdx.x, &blk, &n, &which);
    const int* c = which == 0 ? cs : which == 1 ? cd : which == 2 ? ca : cl;
    int* o = which == 0 ? soff : which == 1 ? doff : which == 2 ? aoff : loff;
    int tx = threadIdx.x, lane = tx & 63, w = tx >> 6;
    int i0 = blk * 1024 + tx * 4;
    int v[4];
#pragma unroll
    for (int q = 0; q < 4; ++q) v[q] = (i0 + q < n) ? c[i0 + q] : 0;
    int s = v[0] + v[1] + v[2] + v[3];
    int inc = s;
#pragma unroll
    for (int d = 1; d < 64; d <<= 1) {
        int u = __shfl_up(inc, d, 64);
        if (lane >= d) inc += u;
    }
    __shared__ int wsum[4];
    if (lane == 63) wsum[w] = inc;
    __syncthreads();
    int wo = 0;
    for (int i = 0; i < w; ++i) wo += wsum[i];
    int run = wo + inc - s;
#pragma unroll
    for (int q = 0; q < 4; ++q) {
        if (i0 + q < n) o[i0 + q] = run;
        run += v[q];
    }
    if (tx == 255) bsum[blockIdx.x] = wo + inc;
}
__global__ __launch_bounds__(128) void k_scan2(
    int* __restrict__ bsum, int* __restrict__ soff, int* __restrict__ doff,
    int* __restrict__ aoff, int* __restrict__ loff) {
    int bx = blockIdx.x;
    int nb   = (bx < 2) ? NBS : NBA;
    int base = (bx == 0) ? 0 : (bx == 1) ? NBS : (bx == 2) ? 2 * NBS : 2 * NBS + NBA;
    int* b = bsum + base;
    int tx = threadIdx.x, lane = tx & 63;
    int v = (tx < nb) ? b[tx] : 0;
    int inc = v;
#pragma unroll
    for (int d = 1; d < 64; d <<= 1) {
        int u = __shfl_up(inc, d, 64);
        if (lane >= d) inc += u;
    }
    __shared__ int w0;
    if (tx == 63) w0 = inc;
    __syncthreads();
    int excl = inc - v + ((tx >= 64) ? w0 : 0);
    if (tx < nb) b[tx] = excl;
    if (tx == nb - 1) {
        int tot = excl + v;
        if (bx == 0) soff[N_ATOMS] = tot;
        else if (bx == 1) doff[N_ATOMS] = tot;
        else if (bx == 2) aoff[N_AMINO] = tot;
        else loff[N_AMINO] = tot;
    }
}
__global__ __launch_bounds__(256) void k_scan3(
    int* __restrict__ soff, int* __restrict__ doff,
    int* __restrict__ aoff, int* __restrict__ loff,
    const int* __restrict__ bsum,
    int* __restrict__ us, int* __restrict__ ud,
    int* __restrict__ ua, int* __restrict__ ul) {
    int blk, n, which;
    seg_decode(blockIdx.x, &blk, &n, &which);
    int* o = which == 0 ? soff : which == 1 ? doff : which == 2 ? aoff : loff;
    int* cu = which == 0 ? us : which == 1 ? ud : which == 2 ? ua : ul;
    int add = bsum[blockIdx.x];
    int i0 = blk * 1024 + threadIdx.x * 4;
#pragma unroll
    for (int q = 0; q < 4; ++q)
        if (i0 + q < n) { int val = o[i0 + q] + add; o[i0 + q] = val; cu[i0 + q] = val; }
}
// fill: src slots -> srcP/eaP(bf16 x11 + 1.0 pad) + sdp (src-slot -> dst-pos),
// amino eids+nrm, label->node
__global__ __launch_bounds__(256) void k_csr_fill(
    const int* __restrict__ esrc, const int* __restrict__ edst,
    const float* __restrict__ ea,
    int* __restrict__ us, int* __restrict__ srcP, u16* __restrict__ eaP,
    int* __restrict__ ud, int* __restrict__ sdp,
    const int* __restrict__ aei, int* __restrict__ ua, int* __restrict__ aeid,
    const int* __restrict__ aoff, float* __restrict__ nrm,
    const int* __restrict__ lbl, int* __restrict__ ul, int* __restrict__ lnid) {
    int t = blockIdx.x * 256 + threadIdx.x;
    if (t < E_ATOMS) {
        int jj = atomicAdd(us + esrc[t], 1);
        srcP[jj] = esrc[t];
        const float* e0 = ea + (size_t)t * D_E;
        u16* e1 = eaP + (size_t)jj * EAW;
#pragma unroll
        for (int k = 0; k < D_E; ++k) e1[k] = f2b(e0[k]);
        e1[D_E] = f2b(1.0f);   // pad = 1.0: folds edge-MLP bias into the 12-dot
        sdp[jj] = atomicAdd(ud + edst[t], 1);   // dst-CSR position for this edge
    } else if (t < E_ATOMS + E_AMINO) {
        int e = t - E_ATOMS;
        int p = atomicAdd(ua + aei[E_AMINO + e], 1);
        aeid[p] = e;
    } else if (t < E_ATOMS + 2 * E_AMINO) {
        int e = t - E_ATOMS - E_AMINO;
        int s = aei[e], d = aei[E_AMINO + e];
        int ds = aoff[s + 1] - aoff[s], dd = aoff[d + 1] - aoff[d];
        float a = ds > 0 ? rsqrtf((float)ds) : 0.f;
        float b = dd > 0 ? rsqrtf((float)dd) : 0.f;
        nrm[e] = a * b;
    } else if (t < E_ATOMS + 2 * E_AMINO + N_ATOMS) {
        int n = t - E_ATOMS - 2 * E_AMINO;
        int p = atomicAdd(ul + lbl[n], 1);
        lnid[p] = n;
    }
}

// ---------------------------------------------------------------------------
// NNConv edge v11 (the 469-us build's kernel, verbatim): MFMA phase-1 over 17
// col-tiles (240 msg-dot cols -> packed y3; 20 root cols -> selfm = x@root +
// bias). Phase 2: 20 lanes/edge, scalar u16 store, dst-ordered msg.
// R12/R15 lesson: the 2-output u32 phase-2 variant regressed 44 -> 61.5 us.
template <int DIN, int KB, bool RAW>
__global__ __launch_bounds__(256, 6) void nnconv_edge11(
    const void* __restrict__ xin, const u16* __restrict__ eaP,
    const int* __restrict__ srcP, const int* __restrict__ sdp,
    const int* __restrict__ soff, const u16* __restrict__ Mb,
    const float* __restrict__ bnn, u16* __restrict__ msg,
    u16* __restrict__ selfm) {
    constexpr int KPAD = KB * 32;
    __shared__ __align__(16) float y3[NTILE * 240];
    __shared__ __align__(16) u16 As[NTILE * KPAD];
    __shared__ __align__(16) float eaS[ECAP * 12];
    __shared__ int srcS[ECAP];
    __shared__ int sdpS[ECAP];
    int tx = threadIdx.x;
    int n0 = blockIdx.x * NTILE;         // N_ATOMS % NTILE == 0
    int j0 = soff[n0], j1 = soff[n0 + NTILE];
    // stage X as bf16 A-fragments (node-major rows, zero-pad k >= DIN)
    for (int i = tx; i < NTILE * KPAD; i += 256) {
        int node = i / KPAD, k = i % KPAD;
        u16 v = 0;
        if (k < DIN)
            v = RAW ? f2b(((const float*)xin)[(size_t)(n0 + node) * DIN + k])
                    : ((const u16*)xin)[(size_t)(n0 + node) * DIN + k];
        As[i] = v;
    }
    // stage phase-2 chunk 0
    {
        int cn0 = j1 - j0; if (cn0 > ECAP) cn0 = ECAP;
        for (int i = tx; i < cn0; i += 256) {
            srcS[i] = srcP[j0 + i] - n0;
            sdpS[i] = sdp[j0 + i];
        }
        const u32* eg = (const u32*)(eaP + (size_t)j0 * EAW);
        for (int i = tx; i < cn0 * 6; i += 256) {
            u32 pv = eg[i];
            eaS[2 * i]     = b2f((u16)(pv & 0xffff));
            eaS[2 * i + 1] = b2f((u16)(pv >> 16));
        }
    }
    __syncthreads();
    // phase 1: MFMA over 17 col-tiles; wave handles ct = wave, wave+4, ...
    {
        int wave = tx >> 6, lane = tx & 63;
        int m = lane & 15, q = lane >> 4;
        short8 aF[KB];
#pragma unroll
        for (int kb = 0; kb < KB; ++kb)
            aF[kb] = *(const short8*)&As[m * KPAD + kb * 32 + q * 8];
        for (int ct = wave; ct < 17; ct += 4) {
            int c0 = ct * 16;
            f32x4 acc = {0.f, 0.f, 0.f, 0.f};
#pragma unroll
            for (int kb = 0; kb < KB; ++kb) {
                short8 bF = *(const short8*)(Mb + (size_t)kb * 8704 + (size_t)(c0 + m) * 32 + q * 8);
                acc = __builtin_amdgcn_mfma_f32_16x16x32_bf16(aF[kb], bF, acc, 0, 0, 0);
            }
            int c = c0 + m;
            if (c < 240) {
                int slot = (c < 220) ? (c % 20) * 12 + c / 20 : (c - 220) * 12 + 11;
#pragma unroll
                for (int r = 0; r < 4; ++r)
                    y3[(q * 4 + r) * 240 + slot] = acc[r];
            } else if (c < 260) {
                float bv = bnn[c - 240];
#pragma unroll
                for (int r = 0; r < 4; ++r)
                    selfm[(size_t)(n0 + q * 4 + r) * HD + (c - 240)] = f2b(acc[r] + bv);
            }
        }
    }
    __syncthreads();
    // phase 2: LDS-only; task p = (edge e, out o); 12-dot; msg in dst order
    int c0 = j0;
    while (true) {
        int cn = j1 - c0; if (cn > ECAP) cn = ECAP;
        for (int p = tx; p < cn * 20; p += 256) {
            int e = p / 20, o = p - e * 20;
            const float4* ev = (const float4*)&eaS[e * 12];
            const float4* yr = (const float4*)&y3[srcS[e] * 240 + o * 12];
            float4 e0 = ev[0], e1 = ev[1], e2 = ev[2];
            float4 q0 = yr[0], q1 = yr[1], q2 = yr[2];
            float mv = e0.x * q0.x + e0.y * q0.y + e0.z * q0.z + e0.w * q0.w
                     + e1.x * q1.x + e1.y * q1.y + e1.z * q1.z + e1.w * q1.w
                     + e2.x * q2.x + e2.y * q2.y + e2.z * q2.z + e2.w * q2.w;
            msg[(size_t)sdpS[e] * 20 + o] = f2b(mv);
        }
        c0 += cn;
        if (c0 >= j1) break;
        // rare: tile had >ECAP edges — restage next chunk
        __syncthreads();
        int cm = j1 - c0; if (cm > ECAP) cm = ECAP;
        for (int i = tx; i < cm; i += 256) {
            srcS[i] = srcP[c0 + i] - n0;
            sdpS[i] = sdp[c0 + i];
        }
        const u32* eg = (const u32*)(eaP + (size_t)c0 * EAW);
        for (int i = tx; i < cm * 6; i += 256) {
            u32 pv = eg[i];
            eaS[2 * i]     = b2f((u16)(pv & 0xffff));
            eaS[2 * i + 1] = b2f((u16)(pv >> 16));
        }
        __syncthreads();
    }
}

// NNConv reduce v2: pure streaming. h = relu(selfm + sum of contiguous
// dst-ordered msg rows). No x, no root, no indirection.
__global__ __launch_bounds__(256) void nnconv_reduce2(
    const u16* __restrict__ selfm, const int* __restrict__ doff,
    const u16* __restrict__ msg, u16* __restrict__ hout) {
    int t = blockIdx.x * 256 + threadIdx.x;
    if (t >= N_ATOMS * HD) return;
    int n = t / HD, o = t - n * HD;
    float acc = b2f(selfm[t]);
    int j1 = doff[n + 1];
    for (int j = doff[n]; j < j1; ++j)
        acc += b2f(msg[(size_t)j * HD + o]);
    hout[t] = f2b(fmaxf(acc, 0.f));
}

// aa gather: label-CSR segmented sum of h3
__global__ __launch_bounds__(256) void aa_gather(
    const u16* __restrict__ h3, const int* __restrict__ loff,
    const int* __restrict__ lnid, float* __restrict__ aa) {
    int t = blockIdx.x * 256 + threadIdx.x;
    if (t >= N_AMINO * HD) return;
    int m = t / HD, o = t % HD;
    float s = 0.f;
    int j1 = loff[m + 1];
    for (int j = loff[m]; j < j1; ++j)
        s += b2f(h3[(size_t)lnid[j] * HD + o]);
    aa[m * 28 + o] = s;
}

// ---------------------------------------------------------------------------
// k_gaa: build A0[10240][64] bf16 = [gather(aa)(28) | aa(28) | 0(8)].
__global__ __launch_bounds__(256) void k_gaa(
    const float* __restrict__ aa, const int* __restrict__ aoff,
    const int* __restrict__ aeid, const int* __restrict__ aei,
    const float* __restrict__ nrm, u16* __restrict__ A0) {
    int t = blockIdx.x * 256 + threadIdx.x;
    if (t >= N_AMINO * 64) return;
    int n = t >> 6, c = t & 63;
    float v = 0.f;
    if (c < 28) {
        int j1 = aoff[n + 1];
        for (int jj = aoff[n]; jj < j1; ++jj) {
            int e = aeid[jj], s = aei[e];
            v += nrm[e] * aa[(size_t)s * 28 + c];
        }
    } else if (c < 56) {
        v = aa[(size_t)n * 28 + (c - 28)];
    }
    A0[t] = f2b(v);
}

// ARMA layer 0: O = relu(A0 @ [init;root0] + bias). Pure MFMA, A0 global.
__global__ __launch_bounds__(256) void arma_l0(
    const u16* __restrict__ A0, const u16* __restrict__ Wp0,
    const float* __restrict__ abi, u16* __restrict__ O, size_t kstride) {
    int wave = threadIdx.x >> 6, lane = threadIdx.x & 63;
    int k = blockIdx.y;
    const u16* W = Wp0 + (size_t)k * 8192;
    u16* Ok = O + (size_t)k * kstride;
    const float* bk = abi + (size_t)k * HA;   // abi[t=0][k][:]
    int n0 = (blockIdx.x * 4 + wave) * 16;
    int m = lane & 15, q = lane >> 4;
    short8 aF[2];
#pragma unroll
    for (int kb = 0; kb < 2; ++kb)
        aF[kb] = *(const short8*)(A0 + (size_t)(n0 + m) * 64 + kb * 32 + q * 8);
#pragma unroll
    for (int ct = 0; ct < 8; ++ct) {
        int c0 = ct * 16;
        float b = bk[c0 + m];
        f32x4 acc = {b, b, b, b};
#pragma unroll
        for (int kb = 0; kb < 2; ++kb) {
            short8 bF = *(const short8*)(W + (size_t)((kb * 128 + c0 + m) * 32 + q * 8));
            acc = __builtin_amdgcn_mfma_f32_16x16x32_bf16(aF[kb], bF, acc, 0, 0, 0);
        }
#pragma unroll
        for (int r = 0; r < 4; ++r)
            Ok[(size_t)(n0 + q * 4 + r) * HA + c0 + m] = f2b(fmaxf(acc[r], 0.f));
    }
}

// ARMA layer t>=1 fused, 32-node tiles (R17: 480 -> 960 blocks; the arma_l0f
// lesson says these layers are latency-bound and block-starved at 1.9
// blocks/CU). Gather G=sum nrm*Oprev[src] into LDS (+aa cols), then
// O = relu([G|aa] @ [W;root] + bias) via MFMA (K=160).
// MFMA phase: wave w -> rows (w>>1)*16, col-tiles (w&1)*4..+4.
__global__ __launch_bounds__(256) void arma_lt32(
    const u16* __restrict__ Oprev, const u16* __restrict__ Wm,
    const float* __restrict__ abit, const float* __restrict__ aa,
    const int* __restrict__ aoff, const int* __restrict__ aeid,
    const int* __restrict__ aei, const float* __restrict__ nrm,
    u16* __restrict__ Onext, size_t kstride) {
    __shared__ __align__(16) u16 As[32 * 160];
    int tx = threadIdx.x;
    int k = blockIdx.y;
    int n0b = blockIdx.x * 32;
    const u16* Op = Oprev + (size_t)k * kstride;
    const u16* W  = Wm + (size_t)k * 20480;   // per-stack weight offset
    // gather phase: 512 tasks = 32 nodes x 16 col-blocks (8 bf16 each)
    for (int i = tx; i < 512; i += 256) {
        int nl = i >> 4, cb = i & 15;
        int n = n0b + nl;
        int j1 = aoff[n + 1];
        float a0 = 0.f, a1 = 0.f, a2 = 0.f, a3 = 0.f;
        float a4 = 0.f, a5 = 0.f, a6 = 0.f, a7 = 0.f;
        for (int jj = aoff[n]; jj < j1; ++jj) {
            int e = aeid[jj], s = aei[e];
            float nm = nrm[e];
            uint4 hv = *(const uint4*)(Op + (size_t)s * HA + cb * 8);
            a0 += nm * b2f((u16)(hv.x & 0xffff));
            a1 += nm * b2f((u16)(hv.x >> 16));
            a2 += nm * b2f((u16)(hv.y & 0xffff));
            a3 += nm * b2f((u16)(hv.y >> 16));
            a4 += nm * b2f((u16)(hv.z & 0xffff));
            a5 += nm * b2f((u16)(hv.z >> 16));
            a6 += nm * b2f((u16)(hv.w & 0xffff));
            a7 += nm * b2f((u16)(hv.w >> 16));
        }
        uint4 pk;
        pk.x = (u32)f2b(a0) | ((u32)f2b(a1) << 16);
        pk.y = (u32)f2b(a2) | ((u32)f2b(a3) << 16);
        pk.z = (u32)f2b(a4) | ((u32)f2b(a5) << 16);
        pk.w = (u32)f2b(a6) | ((u32)f2b(a7) << 16);
        *(uint4*)&As[nl * 160 + cb * 8] = pk;
    }
    // aa cols 128..159: 128 tasks = 32 nodes x 4 col-blocks
    if (tx < 128) {
        int nl = tx >> 2, cb = tx & 3;
        int n = n0b + nl;
        float av[8];
#pragma unroll
        for (int j = 0; j < 8; ++j) {
            int c = cb * 8 + j;
            av[j] = (c < 28) ? aa[(size_t)n * 28 + c] : 0.f;
        }
        uint4 pk;
        pk.x = (u32)f2b(av[0]) | ((u32)f2b(av[1]) << 16);
        pk.y = (u32)f2b(av[2]) | ((u32)f2b(av[3]) << 16);
        pk.z = (u32)f2b(av[4]) | ((u32)f2b(av[5]) << 16);
        pk.w = (u32)f2b(av[6]) | ((u32)f2b(av[7]) << 16);
        *(uint4*)&As[nl * 160 + 128 + cb * 8] = pk;
    }
    __syncthreads();
    // MFMA phase: wave w -> row-tile (w>>1), col-tiles (w&1)*4 .. +4
    int wave = tx >> 6, lane = tx & 63;
    int m = lane & 15, q = lane >> 4;
    int rt = wave >> 1, ch = wave & 1;
    int wl = rt * 16 + m;
    short8 aF[5];
#pragma unroll
    for (int kb = 0; kb < 5; ++kb)
        aF[kb] = *(const short8*)&As[wl * 160 + kb * 32 + q * 8];
    int n0 = n0b + rt * 16;
    u16* On = Onext + (size_t)k * kstride;
    const float* bk = abit + (size_t)k * HA;
#pragma unroll
    for (int ci = 0; ci < 4; ++ci) {
        int c0 = (ch * 4 + ci) * 16;
        float b = bk[c0 + m];
        f32x4 acc = {b, b, b, b};
#pragma unroll
        for (int kb = 0; kb < 5; ++kb) {
            short8 bF = *(const short8*)(W + (size_t)((kb * 128 + c0 + m) * 32 + q * 8));
            acc = __builtin_amdgcn_mfma_f32_16x16x32_bf16(aF[kb], bF, acc, 0, 0, 0);
        }
#pragma unroll
        for (int r = 0; r < 4; ++r)
            On[(size_t)(n0 + q * 4 + r) * HA + c0 + m] = f2b(fmaxf(acc[r], 0.f));
    }
}

// ---------------------------------------------------------------------------
// head2: fused readout (sorted amino_batch segmented sum over bf16 O) + MLP.
__global__ __launch_bounds__(256) void head2(
    const u16* __restrict__ O, size_t kstride, const int* __restrict__ bat,
    const float* __restrict__ l1w, const float* __restrict__ l1b,
    const float* __restrict__ l2w, const float* __restrict__ l2b,
    const float* __restrict__ l3w, const float* __restrict__ l3b,
    const float* __restrict__ l4w, const float* __restrict__ l4b,
    float* __restrict__ outp) {
    __shared__ float sg[HA], sp1[F1], sp2[F2], sp3[F3];
    int b = blockIdx.x, tx = threadIdx.x;
    int lo = 0, hi = N_AMINO;
    while (lo < hi) { int mid = (lo + hi) >> 1; if (bat[mid] < b) lo = mid + 1; else hi = mid; }
    int s = lo;
    lo = 0; hi = N_AMINO;
    while (lo < hi) { int mid = (lo + hi) >> 1; if (bat[mid] < b + 1) lo = mid + 1; else hi = mid; }
    int e = lo;
    if (tx < HA) {
        float acc = 0.f;
        for (int n = s; n < e; ++n)
            acc += b2f(O[(size_t)n * HA + tx]) + b2f(O[kstride + (size_t)n * HA + tx])
                 + b2f(O[2 * kstride + (size_t)n * HA + tx]);
        sg[tx] = acc * (1.f / 3.f);
    }
    __syncthreads();
    {   float acc = l1b[tx];
        for (int f = 0; f < HA; ++f) acc += sg[f] * l1w[f * F1 + tx];
        sp1[tx] = fmaxf(acc, 0.f); }
    __syncthreads();
    if (tx < F2) {
        float acc = l2b[tx];
        for (int f = 0; f < F1; ++f) acc += sp1[f] * l2w[f * F2 + tx];
        sp2[tx] = fmaxf(acc, 0.f); }
    __syncthreads();
    if (tx < F3) {
        float acc = l3b[tx];
        for (int f = 0; f < F2; ++f) acc += sp2[f] * l3w[f * F3 + tx];
        sp3[tx] = fmaxf(acc, 0.f); }
    __syncthreads();
    if (tx < 64) {
        float p = sp3[tx] * l4w[tx];
        for (int off = 32; off > 0; off >>= 1) p += __shfl_down(p, off, 64);
        if (tx == 0) outp[b] = p + l4b[0];
    }
}

// ---------------------------------------------------------------------------
// Workspace (<= 34,348,288 B, proven available).
#define OFF_M1    ((size_t)0)        // Mb1 bf16 34,816 B
#define OFF_M2    ((size_t)38400)    // Mb2 bf16 17,408 B
#define OFF_M3    ((size_t)57600)    // Mb3 bf16 17,408 B (ends 75,008)
#define OFF_AOFF  ((size_t)76800)
#define OFF_AEID  ((size_t)118016)
#define OFF_NRM   ((size_t)199936)
#define OFF_AA    ((size_t)281856)
#define OFF_HA    ((size_t)2891008)   // 4,000,000 -> 6,891,008
#define OFF_HB    ((size_t)6891008)   // 4,000,000 -> 10,891,008
#define OFF_MSG   ((size_t)10891008)  // 8,000,000 -> 18,891,008
#define OFF_SOFF  ((size_t)18891008)
#define OFF_DOFF  ((size_t)19291136)
#define OFF_DSLOT ((size_t)19691264)  // sdp: src-slot -> dst-pos
#define OFF_LOFF  ((size_t)20491264)
#define OFF_LNID  ((size_t)20532480)
#define OFF_CS    ((size_t)20932480)
#define OFF_CD    ((size_t)21332480)
#define OFF_CA    ((size_t)21732480)
#define OFF_CL    ((size_t)21773440)
#define OFF_US    ((size_t)21814400)
#define OFF_UD    ((size_t)22214400)
#define OFF_UA    ((size_t)22614400)
#define OFF_UL    ((size_t)22655360)
#define OFF_BSUM  ((size_t)22696320)
#define OFF_EAP   ((size_t)22697216)      // bf16x12 4,800,000 -> 27,497,216
#define OFF_SRCP  ((size_t)27497216)      // 800,000 -> 28,297,216
#define OFF_WP    ((size_t)28297216)      // 786,432 -> 29,083,648
#define OFF_SELFM ((size_t)29083648)      // bf16 4,000,000 -> 33,083,648
// ARMA overlays (NNConv buffers dead by then):
//   OB (odd-layer O): 2,891,008..10,755,328  (over hA/hB)
//   A0: 10,891,008 + 1,310,720 = 12,201,728  (over msg, dead after reduce2 #3)
//   OA (even-layer O): 18,619,648..26,483,968 (over msg tail + eaP)
#define OFF_OB    ((size_t)2891008)
#define OFF_A0    ((size_t)10891008)
#define OFF_OA    ((size_t)18619648)

extern "C" void kernel_launch(void* const* d_in, const int* in_sizes, int n_in,
                              void* d_out, int out_size, void* d_ws, size_t ws_size,
                              hipStream_t stream) {
    (void)in_sizes; (void)n_in; (void)out_size; (void)ws_size;
    const float* x   = (const float*)d_in[0];
    const int*   ei  = (const int*)d_in[1];
    const float* ea  = (const float*)d_in[2];
    const int*   lbl = (const int*)d_in[3];
    const float* af  = (const float*)d_in[4];
    const int*   aei = (const int*)d_in[5];
    const int*   bat = (const int*)d_in[6];
    const float* nn1w = (const float*)d_in[7];  const float* nn1b = (const float*)d_in[8];
    const float* rt1  = (const float*)d_in[9];  const float* b1   = (const float*)d_in[10];
    const float* nn2w = (const float*)d_in[11]; const float* nn2b = (const float*)d_in[12];
    const float* rt2  = (const float*)d_in[13]; const float* b2   = (const float*)d_in[14];
    const float* nn3w = (const float*)d_in[15]; const float* nn3b = (const float*)d_in[16];
    const float* rt3  = (const float*)d_in[17]; const float* b3   = (const float*)d_in[18];
    const float* ai   = (const float*)d_in[19]; const float* aw   = (const float*)d_in[20];
    const float* arw  = (const float*)d_in[21]; const float* abi  = (const float*)d_in[22];
    const float* l1w  = (const float*)d_in[23]; const float* l1b  = (const float*)d_in[24];
    const float* l2w  = (const float*)d_in[25]; const float* l2b  = (const float*)d_in[26];
    const float* l3w  = (const float*)d_in[27]; const float* l3b  = (const float*)d_in[28];
    const float* l4w  = (const float*)d_in[29]; const float* l4b  = (const float*)d_in[30];
    float* outp = (float*)d_out;

    char* ws = (char*)d_ws;
    u16*   Mb1   = (u16*)(ws + OFF_M1);
    u16*   Mb2   = (u16*)(ws + OFF_M2);
    u16*   Mb3   = (u16*)(ws + OFF_M3);
    int*   aoff  = (int*)(ws + OFF_AOFF);
    int*   aeid  = (int*)(ws + OFF_AEID);
    float* nrm   = (float*)(ws + OFF_NRM);
    float* aa    = (float*)(ws + OFF_AA);
    u16*   hA    = (u16*)(ws + OFF_HA);
    u16*   hB    = (u16*)(ws + OFF_HB);
    u16*   msg   = (u16*)(ws + OFF_MSG);
    int*   soff  = (int*)(ws + OFF_SOFF);
    int*   doff  = (int*)(ws + OFF_DOFF);
    int*   sdp   = (int*)(ws + OFF_DSLOT);
    int*   loff  = (int*)(ws + OFF_LOFF);
    int*   lnid  = (int*)(ws + OFF_LNID);
    int*   cs    = (int*)(ws + OFF_CS);
    int*   cd    = (int*)(ws + OFF_CD);
    int*   ca    = (int*)(ws + OFF_CA);
    int*   cl    = (int*)(ws + OFF_CL);
    int*   us    = (int*)(ws + OFF_US);
    int*   ud    = (int*)(ws + OFF_UD);
    int*   ua    = (int*)(ws + OFF_UA);
    int*   ul    = (int*)(ws + OFF_UL);
    int*   bsum  = (int*)(ws + OFF_BSUM);
    u16*   eaP   = (u16*)(ws + OFF_EAP);
    int*   srcP  = (int*)(ws + OFF_SRCP);
    u16*   Wp    = (u16*)(ws + OFF_WP);
    u16*   selfm = (u16*)(ws + OFF_SELFM);
    u16*   A0    = (u16*)(ws + OFF_A0);
    u16*   OA    = (u16*)(ws + OFF_OA);
    u16*   OB    = (u16*)(ws + OFF_OB);

    const int* esrc = ei;
    const int* edst = ei + E_ATOMS;
    const int* adst = aei + E_AMINO;

    // prep (merged prep + weight pack)
    k_prep<<<(PREP_N + 255) / 256, 256, 0, stream>>>(
        nn1w, nn1b, rt1, nn2w, nn2b, rt2, nn3w, nn3b, rt3,
        Mb1, Mb2, Mb3, af, aa, cs, cd, ca, cl, ai, aw, arw, Wp);
    k_csr_count<<<(2 * E_ATOMS + E_AMINO + N_ATOMS + 255) / 256, 256, 0, stream>>>(
        esrc, edst, adst, lbl, cs, cd, ca, cl);
    k_scan1<<<2 * NBS + 2 * NBA, 256, 0, stream>>>(cs, soff, cd, doff, ca, aoff, cl, loff, bsum);
    k_scan2<<<4, 128, 0, stream>>>(bsum, soff, doff, aoff, loff);
    k_scan3<<<2 * NBS + 2 * NBA, 256, 0, stream>>>(soff, doff, aoff, loff, bsum, us, ud, ua, ul);
    k_csr_fill<<<(E_ATOMS + 2 * E_AMINO + N_ATOMS + 255) / 256, 256, 0, stream>>>(
        esrc, edst, ea, us, srcP, eaP, ud, sdp, aei, ua, aeid, aoff, nrm, lbl, ul, lnid);

    // NNConv (edge v11 + separate streaming reduce)
    const int GT = N_ATOMS / NTILE;               // 6250
    const int GF = (N_ATOMS * HD + 255) / 256;    // 7813
    nnconv_edge11<DIN0, 2, true ><<<GT, 256, 0, stream>>>(x,  eaP, srcP, sdp, soff, Mb1, b1, msg, selfm);
    nnconv_reduce2<<<GF, 256, 0, stream>>>(selfm, doff, msg, hA);
    nnconv_edge11<HD,   1, false><<<GT, 256, 0, stream>>>(hA, eaP, srcP, sdp, soff, Mb2, b2, msg, selfm);
    nnconv_reduce2<<<GF, 256, 0, stream>>>(selfm, doff, msg, hB);
    nnconv_edge11<HD,   1, false><<<GT, 256, 0, stream>>>(hB, eaP, srcP, sdp, soff, Mb3, b3, msg, selfm);
    nnconv_reduce2<<<GF, 256, 0, stream>>>(selfm, doff, msg, hA);
    aa_gather<<<(N_AMINO * HD + 255) / 256, 256, 0, stream>>>(hA, loff, lnid, aa);

    // ARMA: gather/GEMM commuted; k_gaa + arma_l0 (R16 proven); lt 32-tiles.
    const size_t KH = (size_t)N_AMINO * HA;
    k_gaa<<<(N_AMINO * 64 + 255) / 256, 256, 0, stream>>>(aa, aoff, aeid, aei, nrm, A0);
    arma_l0<<<dim3(160, KS), 256, 0, stream>>>(A0, Wp, abi, OA, KH);
    for (int t = 1; t < TL; ++t) {
        const u16* Oin  = (t & 1) ? OA : OB;
        u16*       Oout = (t & 1) ? OB : OA;
        arma_lt32<<<dim3(320, KS), 256, 0, stream>>>(
            Oin, Wp + WP0_ELEMS + (size_t)((t - 1) * KS) * 20480,
            abi + (size_t)t * KS * HA, aa, aoff, aeid, aei, nrm, Oout, KH);
    }
    // TL=7: final output (t=6, even) lands in OA.
    head2<<<NGRAPH, 256, 0, stream>>>(OA, KH, bat, l1w, l1b, l2w, l2b,
                                      l3w, l3b, l4w, l4b, outp);
}

// Round 22
// 435.160 us; speedup vs baseline: 1.2399x; 1.0176x over previous
//
#include <hip/hip_runtime.h>

#define N_ATOMS 100000
#define E_ATOMS 200000
#define N_AMINO 10240
#define E_AMINO 20480
#define NGRAPH 512
#define DIN0 40
#define D_E 11
#define HD 20
#define D_AA 8
#define HA 128
#define KS 3
#define TL 7
#define F1 256
#define F2 128
#define F3 64
#define NTILE 16  // nodes per edge-kernel tile (100000 % 16 == 0)
#define ECAP 64   // staged edges per chunk (mean 32/tile; loop handles overflow)
#define EAW 12    // eaP row (u16): 11 attrs + 1.0 pad; 24 B, u32-aligned

typedef unsigned short u16;
typedef unsigned int u32;
typedef __attribute__((ext_vector_type(8))) short short8;
typedef __attribute__((ext_vector_type(4))) float f32x4;

__device__ __forceinline__ float b2f(u16 u) {
    union { u32 i; float f; } v; v.i = ((u32)u) << 16; return v.f;
}
__device__ __forceinline__ u16 f2b(float f) {
    union { float f; u32 i; } v; v.f = f;
    u32 x = v.i;
    return (u16)((x + (((x >> 16) & 1u) + 0x7fffu)) >> 16);
}

// ---------------------------------------------------------------------------
// k_prep: merged prep + ARMA weight pack.
// Part A: Mb matrices in MFMA B-fragment order (bf16; 272 padded cols =
// W(220)|edge-bias(20)|root(20)|0(12), K padded to 32*KB) + aa feature cols
// + zero CSR counts.  Part B: ARMA weight pack (Wp).
#define MB1_ELEMS 17408   // DIN=40 -> KB=2, 2*8704
#define MB2_ELEMS 8704    // DIN=20 -> KB=1
#define PREP0_N (MB1_ELEMS + 2 * MB2_ELEMS + N_AMINO * D_AA + 2 * N_ATOMS + 2 * N_AMINO)
#define WP0_ELEMS (KS * 8192)
#define WP1_ELEMS (6 * KS * 20480)
#define PREP_N (PREP0_N + WP0_ELEMS + WP1_ELEMS)
__global__ __launch_bounds__(256) void k_prep(
    const float* __restrict__ w1, const float* __restrict__ nb1, const float* __restrict__ r1,
    const float* __restrict__ w2, const float* __restrict__ nb2, const float* __restrict__ r2,
    const float* __restrict__ w3, const float* __restrict__ nb3, const float* __restrict__ r3,
    u16* __restrict__ Mb1, u16* __restrict__ Mb2, u16* __restrict__ Mb3,
    const float* __restrict__ af, float* __restrict__ aa,
    int* __restrict__ cs, int* __restrict__ cd,
    int* __restrict__ ca, int* __restrict__ cl,
    const float* __restrict__ ai, const float* __restrict__ aw,
    const float* __restrict__ arw, u16* __restrict__ Wp) {
    int t = blockIdx.x * 256 + threadIdx.x;
    if (t < MB1_ELEMS) {
        int kb = t / 8704, rem = t % 8704;
        int c = rem >> 5, qj = rem & 31;
        int krow = kb * 32 + qj;
        float v = 0.f;
        if (krow < DIN0) {
            if (c < 220)      v = w1[(c / 20) * 800 + krow * 20 + (c % 20)];
            else if (c < 240) v = nb1[krow * 20 + (c - 220)];
            else if (c < 260) v = r1[krow * 20 + (c - 240)];
        }
        Mb1[t] = f2b(v);
    } else if (t < MB1_ELEMS + MB2_ELEMS) {
        int tt = t - MB1_ELEMS;
        int c = tt >> 5, qj = tt & 31;
        float v = 0.f;
        if (qj < HD) {
            if (c < 220)      v = w2[(c / 20) * 400 + qj * 20 + (c % 20)];
            else if (c < 240) v = nb2[qj * 20 + (c - 220)];
            else if (c < 260) v = r2[qj * 20 + (c - 240)];
        }
        Mb2[tt] = f2b(v);
    } else if (t < MB1_ELEMS + 2 * MB2_ELEMS) {
        int tt = t - MB1_ELEMS - MB2_ELEMS;
        int c = tt >> 5, qj = tt & 31;
        float v = 0.f;
        if (qj < HD) {
            if (c < 220)      v = w3[(c / 20) * 400 + qj * 20 + (c % 20)];
            else if (c < 240) v = nb3[qj * 20 + (c - 220)];
            else if (c < 260) v = r3[qj * 20 + (c - 240)];
        }
        Mb3[tt] = f2b(v);
    } else if (t < MB1_ELEMS + 2 * MB2_ELEMS + N_AMINO * D_AA) {
        int idx = t - MB1_ELEMS - 2 * MB2_ELEMS, m = idx / D_AA, j = idx % D_AA;
        aa[m * 28 + HD + j] = af[idx];
    } else if (t < PREP0_N) {
        int z = t - MB1_ELEMS - 2 * MB2_ELEMS - N_AMINO * D_AA;
        if (z < N_ATOMS) cs[z] = 0;
        else if (z < 2 * N_ATOMS) cd[z - N_ATOMS] = 0;
        else if (z < 2 * N_ATOMS + N_AMINO) ca[z - 2 * N_ATOMS] = 0;
        else if (z < 2 * N_ATOMS + 2 * N_AMINO) cl[z - 2 * N_ATOMS - N_AMINO] = 0;
    } else {
        int g = t - PREP0_N;
        if (g < WP0_ELEMS) {
            int k = g / 8192, r = g % 8192;
            int kb = r >> 12, rem = r & 4095;
            int c = rem >> 5, qj = rem & 31;
            int krow = kb * 32 + qj;
            float v = 0.f;
            if (krow < 28)      v = ai[((size_t)k * 28 + krow) * HA + c];
            else if (krow < 56) v = arw[((size_t)k * 28 + (krow - 28)) * HA + c];
            Wp[g] = f2b(v);
        } else if (g < WP0_ELEMS + WP1_ELEMS) {
            int gg = g - WP0_ELEMS;
            int mat = gg / 20480, r = gg % 20480;
            int kb = r / 4096, rem = r & 4095;
            int c = rem >> 5, qj = rem & 31;
            int krow = kb * 32 + qj;
            int tm1 = mat / KS, k = mat % KS;
            float v = 0.f;
            if (krow < 128)      v = aw[((size_t)mat * 128 + krow) * HA + c];
            else if (krow < 156) v = arw[(((size_t)(tm1 + 1) * KS + k) * 28 + (krow - 128)) * HA + c];
            Wp[g] = f2b(v);
        }
    }
}

// ---------------------------------------------------------------------------
#define NBS 98
#define NBA 10

__global__ __launch_bounds__(256) void k_csr_count(
    const int* __restrict__ esrc, const int* __restrict__ edst,
    const int* __restrict__ adst, const int* __restrict__ lbl,
    int* __restrict__ cs, int* __restrict__ cd,
    int* __restrict__ ca, int* __restrict__ cl) {
    int t = blockIdx.x * 256 + threadIdx.x;
    if (t < E_ATOMS) atomicAdd(cs + esrc[t], 1);
    else if (t < 2 * E_ATOMS) atomicAdd(cd + edst[t - E_ATOMS], 1);
    else if (t < 2 * E_ATOMS + E_AMINO) atomicAdd(ca + adst[t - 2 * E_ATOMS], 1);
    else if (t < 2 * E_ATOMS + E_AMINO + N_ATOMS) atomicAdd(cl + lbl[t - 2 * E_ATOMS - E_AMINO], 1);
}
__device__ __forceinline__ void seg_decode(int bx, int* blk, int* n, int* which) {
    if (bx < NBS)            { *which = 0; *blk = bx;             *n = N_ATOMS; }
    else if (bx < 2 * NBS)   { *which = 1; *blk = bx - NBS;       *n = N_ATOMS; }
    else if (bx < 2 * NBS + NBA) { *which = 2; *blk = bx - 2 * NBS; *n = N_AMINO; }
    else                     { *which = 3; *blk = bx - 2 * NBS - NBA; *n = N_AMINO; }
}
__global__ __launch_bounds__(256) void k_scan1(
    const int* __restrict__ cs, int* __restrict__ soff,
    const int* __restrict__ cd, int* __restrict__ doff,
    const int* __restrict__ ca, int* __restrict__ aoff,
    const int* __restrict__ cl, int* __restrict__ loff,
    int* __restrict__ bsum) {
    int blk, n, which;
    seg_decode(blockIdx.x, &blk, &n, &which);
    const int* c = which == 0 ? cs : which == 1 ? cd : which == 2 ? ca : cl;
    int* o = which == 0 ? soff : which == 1 ? doff : which == 2 ? aoff : loff;
    int tx = threadIdx.x, lane = tx & 63, w = tx >> 6;
    int i0 = blk * 1024 + tx * 4;
    int v[4];
#pragma unroll
    for (int q = 0; q < 4; ++q) v[q] = (i0 + q < n) ? c[i0 + q] : 0;
    int s = v[0] + v[1] + v[2] + v[3];
    int inc = s;
#pragma unroll
    for (int d = 1; d < 64; d <<= 1) {
        int u = __shfl_up(inc, d, 64);
        if (lane >= d) inc += u;
    }
    __shared__ int wsum[4];
    if (lane == 63) wsum[w] = inc;
    __syncthreads();
    int wo = 0;
    for (int i = 0; i < w; ++i) wo += wsum[i];
    int run = wo + inc - s;
#pragma unroll
    for (int q = 0; q < 4; ++q) {
        if (i0 + q < n) o[i0 + q] = run;
        run += v[q];
    }
    if (tx == 255) bsum[blockIdx.x] = wo + inc;
}
__global__ __launch_bounds__(128) void k_scan2(
    int* __restrict__ bsum, int* __restrict__ soff, int* __restrict__ doff,
    int* __restrict__ aoff, int* __restrict__ loff) {
    int bx = blockIdx.x;
    int nb   = (bx < 2) ? NBS : NBA;
    int base = (bx == 0) ? 0 : (bx == 1) ? NBS : (bx == 2) ? 2 * NBS : 2 * NBS + NBA;
    int* b = bsum + base;
    int tx = threadIdx.x, lane = tx & 63;
    int v = (tx < nb) ? b[tx] : 0;
    int inc = v;
#pragma unroll
    for (int d = 1; d < 64; d <<= 1) {
        int u = __shfl_up(inc, d, 64);
        if (lane >= d) inc += u;
    }
    __shared__ int w0;
    if (tx == 63) w0 = inc;
    __syncthreads();
    int excl = inc - v + ((tx >= 64) ? w0 : 0);
    if (tx < nb) b[tx] = excl;
    if (tx == nb - 1) {
        int tot = excl + v;
        if (bx == 0) soff[N_ATOMS] = tot;
        else if (bx == 1) doff[N_ATOMS] = tot;
        else if (bx == 2) aoff[N_AMINO] = tot;
        else loff[N_AMINO] = tot;
    }
}
__global__ __launch_bounds__(256) void k_scan3(
    int* __restrict__ soff, int* __restrict__ doff,
    int* __restrict__ aoff, int* __restrict__ loff,
    const int* __restrict__ bsum,
    int* __restrict__ us, int* __restrict__ ud,
    int* __restrict__ ua, int* __restrict__ ul) {
    int blk, n, which;
    seg_decode(blockIdx.x, &blk, &n, &which);
    int* o = which == 0 ? soff : which == 1 ? doff : which == 2 ? aoff : loff;
    int* cu = which == 0 ? us : which == 1 ? ud : which == 2 ? ua : ul;
    int add = bsum[blockIdx.x];
    int i0 = blk * 1024 + threadIdx.x * 4;
#pragma unroll
    for (int q = 0; q < 4; ++q)
        if (i0 + q < n) { int val = o[i0 + q] + add; o[i0 + q] = val; cu[i0 + q] = val; }
}
// fill: src slots -> srcP/eaP(bf16 x11 + 1.0 pad) + sdp (src-slot -> dst-pos),
// amino eids+nrm, label->node
__global__ __launch_bounds__(256) void k_csr_fill(
    const int* __restrict__ esrc, const int* __restrict__ edst,
    const float* __restrict__ ea,
    int* __restrict__ us, int* __restrict__ srcP, u16* __restrict__ eaP,
    int* __restrict__ ud, int* __restrict__ sdp,
    const int* __restrict__ aei, int* __restrict__ ua, int* __restrict__ aeid,
    const int* __restrict__ aoff, float* __restrict__ nrm,
    const int* __restrict__ lbl, int* __restrict__ ul, int* __restrict__ lnid) {
    int t = blockIdx.x * 256 + threadIdx.x;
    if (t < E_ATOMS) {
        int jj = atomicAdd(us + esrc[t], 1);
        srcP[jj] = esrc[t];
        const float* e0 = ea + (size_t)t * D_E;
        u16* e1 = eaP + (size_t)jj * EAW;
#pragma unroll
        for (int k = 0; k < D_E; ++k) e1[k] = f2b(e0[k]);
        e1[D_E] = f2b(1.0f);   // pad = 1.0: folds edge-MLP bias into the 12-dot
        sdp[jj] = atomicAdd(ud + edst[t], 1);   // dst-CSR position for this edge
    } else if (t < E_ATOMS + E_AMINO) {
        int e = t - E_ATOMS;
        int p = atomicAdd(ua + aei[E_AMINO + e], 1);
        aeid[p] = e;
    } else if (t < E_ATOMS + 2 * E_AMINO) {
        int e = t - E_ATOMS - E_AMINO;
        int s = aei[e], d = aei[E_AMINO + e];
        int ds = aoff[s + 1] - aoff[s], dd = aoff[d + 1] - aoff[d];
        float a = ds > 0 ? rsqrtf((float)ds) : 0.f;
        float b = dd > 0 ? rsqrtf((float)dd) : 0.f;
        nrm[e] = a * b;
    } else if (t < E_ATOMS + 2 * E_AMINO + N_ATOMS) {
        int n = t - E_ATOMS - 2 * E_AMINO;
        int p = atomicAdd(ul + lbl[n], 1);
        lnid[p] = n;
    }
}

// ---------------------------------------------------------------------------
// NNConv edge v11 (the 469-us build's kernel, verbatim): MFMA phase-1 over 17
// col-tiles (240 msg-dot cols -> packed y3; 20 root cols -> selfm = x@root +
// bias). Phase 2: 20 lanes/edge, scalar u16 store, dst-ordered msg.
// R12/R15 lesson: the 2-output u32 phase-2 variant regressed 44 -> 61.5 us.
template <int DIN, int KB, bool RAW>
__global__ __launch_bounds__(256, 6) void nnconv_edge11(
    const void* __restrict__ xin, const u16* __restrict__ eaP,
    const int* __restrict__ srcP, const int* __restrict__ sdp,
    const int* __restrict__ soff, const u16* __restrict__ Mb,
    const float* __restrict__ bnn, u16* __restrict__ msg,
    u16* __restrict__ selfm) {
    constexpr int KPAD = KB * 32;
    __shared__ __align__(16) float y3[NTILE * 240];
    __shared__ __align__(16) u16 As[NTILE * KPAD];
    __shared__ __align__(16) float eaS[ECAP * 12];
    __shared__ int srcS[ECAP];
    __shared__ int sdpS[ECAP];
    int tx = threadIdx.x;
    int n0 = blockIdx.x * NTILE;         // N_ATOMS % NTILE == 0
    int j0 = soff[n0], j1 = soff[n0 + NTILE];
    // stage X as bf16 A-fragments (node-major rows, zero-pad k >= DIN)
    for (int i = tx; i < NTILE * KPAD; i += 256) {
        int node = i / KPAD, k = i % KPAD;
        u16 v = 0;
        if (k < DIN)
            v = RAW ? f2b(((const float*)xin)[(size_t)(n0 + node) * DIN + k])
                    : ((const u16*)xin)[(size_t)(n0 + node) * DIN + k];
        As[i] = v;
    }
    // stage phase-2 chunk 0
    {
        int cn0 = j1 - j0; if (cn0 > ECAP) cn0 = ECAP;
        for (int i = tx; i < cn0; i += 256) {
            srcS[i] = srcP[j0 + i] - n0;
            sdpS[i] = sdp[j0 + i];
        }
        const u32* eg = (const u32*)(eaP + (size_t)j0 * EAW);
        for (int i = tx; i < cn0 * 6; i += 256) {
            u32 pv = eg[i];
            eaS[2 * i]     = b2f((u16)(pv & 0xffff));
            eaS[2 * i + 1] = b2f((u16)(pv >> 16));
        }
    }
    __syncthreads();
    // phase 1: MFMA over 17 col-tiles; wave handles ct = wave, wave+4, ...
    {
        int wave = tx >> 6, lane = tx & 63;
        int m = lane & 15, q = lane >> 4;
        short8 aF[KB];
#pragma unroll
        for (int kb = 0; kb < KB; ++kb)
            aF[kb] = *(const short8*)&As[m * KPAD + kb * 32 + q * 8];
        for (int ct = wave; ct < 17; ct += 4) {
            int c0 = ct * 16;
            f32x4 acc = {0.f, 0.f, 0.f, 0.f};
#pragma unroll
            for (int kb = 0; kb < KB; ++kb) {
                short8 bF = *(const short8*)(Mb + (size_t)kb * 8704 + (size_t)(c0 + m) * 32 + q * 8);
                acc = __builtin_amdgcn_mfma_f32_16x16x32_bf16(aF[kb], bF, acc, 0, 0, 0);
            }
            int c = c0 + m;
            if (c < 240) {
                int slot = (c < 220) ? (c % 20) * 12 + c / 20 : (c - 220) * 12 + 11;
#pragma unroll
                for (int r = 0; r < 4; ++r)
                    y3[(q * 4 + r) * 240 + slot] = acc[r];
            } else if (c < 260) {
                float bv = bnn[c - 240];
#pragma unroll
                for (int r = 0; r < 4; ++r)
                    selfm[(size_t)(n0 + q * 4 + r) * HD + (c - 240)] = f2b(acc[r] + bv);
            }
        }
    }
    __syncthreads();
    // phase 2: LDS-only; task p = (edge e, out o); 12-dot; msg in dst order
    int c0 = j0;
    while (true) {
        int cn = j1 - c0; if (cn > ECAP) cn = ECAP;
        for (int p = tx; p < cn * 20; p += 256) {
            int e = p / 20, o = p - e * 20;
            const float4* ev = (const float4*)&eaS[e * 12];
            const float4* yr = (const float4*)&y3[srcS[e] * 240 + o * 12];
            float4 e0 = ev[0], e1 = ev[1], e2 = ev[2];
            float4 q0 = yr[0], q1 = yr[1], q2 = yr[2];
            float mv = e0.x * q0.x + e0.y * q0.y + e0.z * q0.z + e0.w * q0.w
                     + e1.x * q1.x + e1.y * q1.y + e1.z * q1.z + e1.w * q1.w
                     + e2.x * q2.x + e2.y * q2.y + e2.z * q2.z + e2.w * q2.w;
            msg[(size_t)sdpS[e] * 20 + o] = f2b(mv);
        }
        c0 += cn;
        if (c0 >= j1) break;
        // rare: tile had >ECAP edges — restage next chunk
        __syncthreads();
        int cm = j1 - c0; if (cm > ECAP) cm = ECAP;
        for (int i = tx; i < cm; i += 256) {
            srcS[i] = srcP[c0 + i] - n0;
            sdpS[i] = sdp[c0 + i];
        }
        const u32* eg = (const u32*)(eaP + (size_t)c0 * EAW);
        for (int i = tx; i < cm * 6; i += 256) {
            u32 pv = eg[i];
            eaS[2 * i]     = b2f((u16)(pv & 0xffff));
            eaS[2 * i + 1] = b2f((u16)(pv >> 16));
        }
        __syncthreads();
    }
}

// NNConv reduce v2: pure streaming. h = relu(selfm + sum of contiguous
// dst-ordered msg rows). No x, no root, no indirection.
__global__ __launch_bounds__(256) void nnconv_reduce2(
    const u16* __restrict__ selfm, const int* __restrict__ doff,
    const u16* __restrict__ msg, u16* __restrict__ hout) {
    int t = blockIdx.x * 256 + threadIdx.x;
    if (t >= N_ATOMS * HD) return;
    int n = t / HD, o = t - n * HD;
    float acc = b2f(selfm[t]);
    int j1 = doff[n + 1];
    for (int j = doff[n]; j < j1; ++j)
        acc += b2f(msg[(size_t)j * HD + o]);
    hout[t] = f2b(fmaxf(acc, 0.f));
}

// aa gather: label-CSR segmented sum of h3
__global__ __launch_bounds__(256) void aa_gather(
    const u16* __restrict__ h3, const int* __restrict__ loff,
    const int* __restrict__ lnid, float* __restrict__ aa) {
    int t = blockIdx.x * 256 + threadIdx.x;
    if (t >= N_AMINO * HD) return;
    int m = t / HD, o = t % HD;
    float s = 0.f;
    int j1 = loff[m + 1];
    for (int j = loff[m]; j < j1; ++j)
        s += b2f(h3[(size_t)lnid[j] * HD + o]);
    aa[m * 28 + o] = s;
}

// ---------------------------------------------------------------------------
// k_gaa: build A0[10240][64] bf16 = [gather(aa)(28) | aa(28) | 0(8)].
__global__ __launch_bounds__(256) void k_gaa(
    const float* __restrict__ aa, const int* __restrict__ aoff,
    const int* __restrict__ aeid, const int* __restrict__ aei,
    const float* __restrict__ nrm, u16* __restrict__ A0) {
    int t = blockIdx.x * 256 + threadIdx.x;
    if (t >= N_AMINO * 64) return;
    int n = t >> 6, c = t & 63;
    float v = 0.f;
    if (c < 28) {
        int j1 = aoff[n + 1];
        for (int jj = aoff[n]; jj < j1; ++jj) {
            int e = aeid[jj], s = aei[e];
            v += nrm[e] * aa[(size_t)s * 28 + c];
        }
    } else if (c < 56) {
        v = aa[(size_t)n * 28 + (c - 28)];
    }
    A0[t] = f2b(v);
}

// ARMA layer 0: O = relu(A0 @ [init;root0] + bias). Pure MFMA, A0 global.
__global__ __launch_bounds__(256) void arma_l0(
    const u16* __restrict__ A0, const u16* __restrict__ Wp0,
    const float* __restrict__ abi, u16* __restrict__ O, size_t kstride) {
    int wave = threadIdx.x >> 6, lane = threadIdx.x & 63;
    int k = blockIdx.y;
    const u16* W = Wp0 + (size_t)k * 8192;
    u16* Ok = O + (size_t)k * kstride;
    const float* bk = abi + (size_t)k * HA;   // abi[t=0][k][:]
    int n0 = (blockIdx.x * 4 + wave) * 16;
    int m = lane & 15, q = lane >> 4;
    short8 aF[2];
#pragma unroll
    for (int kb = 0; kb < 2; ++kb)
        aF[kb] = *(const short8*)(A0 + (size_t)(n0 + m) * 64 + kb * 32 + q * 8);
#pragma unroll
    for (int ct = 0; ct < 8; ++ct) {
        int c0 = ct * 16;
        float b = bk[c0 + m];
        f32x4 acc = {b, b, b, b};
#pragma unroll
        for (int kb = 0; kb < 2; ++kb) {
            short8 bF = *(const short8*)(W + (size_t)((kb * 128 + c0 + m) * 32 + q * 8));
            acc = __builtin_amdgcn_mfma_f32_16x16x32_bf16(aF[kb], bF, acc, 0, 0, 0);
        }
#pragma unroll
        for (int r = 0; r < 4; ++r)
            Ok[(size_t)(n0 + q * 4 + r) * HA + c0 + m] = f2b(fmaxf(acc[r], 0.f));
    }
}

// ARMA layer t>=1 fused, 16-node tiles (R22: 960 -> 1920 blocks = 7.5/CU =
// 30 waves/CU, first full-occupancy ARMA config; block-starvation theory
// twice-confirmed at 64->32). Gather G=sum nrm*Oprev[src] into LDS (+aa
// cols), then O = relu([G|aa] @ [W;root] + bias) via MFMA (K=160).
// MFMA phase: wave w -> rows 0..15, col-tiles w*2 .. w*2+2.
__global__ __launch_bounds__(256) void arma_lt16(
    const u16* __restrict__ Oprev, const u16* __restrict__ Wm,
    const float* __restrict__ abit, const float* __restrict__ aa,
    const int* __restrict__ aoff, const int* __restrict__ aeid,
    const int* __restrict__ aei, const float* __restrict__ nrm,
    u16* __restrict__ Onext, size_t kstride) {
    __shared__ __align__(16) u16 As[16 * 160];
    int tx = threadIdx.x;
    int k = blockIdx.y;
    int n0b = blockIdx.x * 16;
    const u16* Op = Oprev + (size_t)k * kstride;
    const u16* W  = Wm + (size_t)k * 20480;   // per-stack weight offset
    // gather phase: 256 tasks = 16 nodes x 16 col-blocks (8 bf16 each), 1/thread
    {
        int nl = tx >> 4, cb = tx & 15;
        int n = n0b + nl;
        int j1 = aoff[n + 1];
        float a0 = 0.f, a1 = 0.f, a2 = 0.f, a3 = 0.f;
        float a4 = 0.f, a5 = 0.f, a6 = 0.f, a7 = 0.f;
        for (int jj = aoff[n]; jj < j1; ++jj) {
            int e = aeid[jj], s = aei[e];
            float nm = nrm[e];
            uint4 hv = *(const uint4*)(Op + (size_t)s * HA + cb * 8);
            a0 += nm * b2f((u16)(hv.x & 0xffff));
            a1 += nm * b2f((u16)(hv.x >> 16));
            a2 += nm * b2f((u16)(hv.y & 0xffff));
            a3 += nm * b2f((u16)(hv.y >> 16));
            a4 += nm * b2f((u16)(hv.z & 0xffff));
            a5 += nm * b2f((u16)(hv.z >> 16));
            a6 += nm * b2f((u16)(hv.w & 0xffff));
            a7 += nm * b2f((u16)(hv.w >> 16));
        }
        uint4 pk;
        pk.x = (u32)f2b(a0) | ((u32)f2b(a1) << 16);
        pk.y = (u32)f2b(a2) | ((u32)f2b(a3) << 16);
        pk.z = (u32)f2b(a4) | ((u32)f2b(a5) << 16);
        pk.w = (u32)f2b(a6) | ((u32)f2b(a7) << 16);
        *(uint4*)&As[nl * 160 + cb * 8] = pk;
    }
    // aa cols 128..159: 64 tasks = 16 nodes x 4 col-blocks
    if (tx < 64) {
        int nl = tx >> 2, cb = tx & 3;
        int n = n0b + nl;
        float av[8];
#pragma unroll
        for (int j = 0; j < 8; ++j) {
            int c = cb * 8 + j;
            av[j] = (c < 28) ? aa[(size_t)n * 28 + c] : 0.f;
        }
        uint4 pk;
        pk.x = (u32)f2b(av[0]) | ((u32)f2b(av[1]) << 16);
        pk.y = (u32)f2b(av[2]) | ((u32)f2b(av[3]) << 16);
        pk.z = (u32)f2b(av[4]) | ((u32)f2b(av[5]) << 16);
        pk.w = (u32)f2b(av[6]) | ((u32)f2b(av[7]) << 16);
        *(uint4*)&As[nl * 160 + 128 + cb * 8] = pk;
    }
    __syncthreads();
    // MFMA phase: wave w -> rows 0..15, col-tiles w*2 .. w*2+2
    int wave = tx >> 6, lane = tx & 63;
    int m = lane & 15, q = lane >> 4;
    short8 aF[5];
#pragma unroll
    for (int kb = 0; kb < 5; ++kb)
        aF[kb] = *(const short8*)&As[m * 160 + kb * 32 + q * 8];
    u16* On = Onext + (size_t)k * kstride;
    const float* bk = abit + (size_t)k * HA;
#pragma unroll
    for (int ci = 0; ci < 2; ++ci) {
        int c0 = (wave * 2 + ci) * 16;
        float b = bk[c0 + m];
        f32x4 acc = {b, b, b, b};
#pragma unroll
        for (int kb = 0; kb < 5; ++kb) {
            short8 bF = *(const short8*)(W + (size_t)((kb * 128 + c0 + m) * 32 + q * 8));
            acc = __builtin_amdgcn_mfma_f32_16x16x32_bf16(aF[kb], bF, acc, 0, 0, 0);
        }
#pragma unroll
        for (int r = 0; r < 4; ++r)
            On[(size_t)(n0b + q * 4 + r) * HA + c0 + m] = f2b(fmaxf(acc[r], 0.f));
    }
}

// ---------------------------------------------------------------------------
// head2: fused readout (sorted amino_batch segmented sum over bf16 O) + MLP.
__global__ __launch_bounds__(256) void head2(
    const u16* __restrict__ O, size_t kstride, const int* __restrict__ bat,
    const float* __restrict__ l1w, const float* __restrict__ l1b,
    const float* __restrict__ l2w, const float* __restrict__ l2b,
    const float* __restrict__ l3w, const float* __restrict__ l3b,
    const float* __restrict__ l4w, const float* __restrict__ l4b,
    float* __restrict__ outp) {
    __shared__ float sg[HA], sp1[F1], sp2[F2], sp3[F3];
    int b = blockIdx.x, tx = threadIdx.x;
    int lo = 0, hi = N_AMINO;
    while (lo < hi) { int mid = (lo + hi) >> 1; if (bat[mid] < b) lo = mid + 1; else hi = mid; }
    int s = lo;
    lo = 0; hi = N_AMINO;
    while (lo < hi) { int mid = (lo + hi) >> 1; if (bat[mid] < b + 1) lo = mid + 1; else hi = mid; }
    int e = lo;
    if (tx < HA) {
        float acc = 0.f;
        for (int n = s; n < e; ++n)
            acc += b2f(O[(size_t)n * HA + tx]) + b2f(O[kstride + (size_t)n * HA + tx])
                 + b2f(O[2 * kstride + (size_t)n * HA + tx]);
        sg[tx] = acc * (1.f / 3.f);
    }
    __syncthreads();
    {   float acc = l1b[tx];
        for (int f = 0; f < HA; ++f) acc += sg[f] * l1w[f * F1 + tx];
        sp1[tx] = fmaxf(acc, 0.f); }
    __syncthreads();
    if (tx < F2) {
        float acc = l2b[tx];
        for (int f = 0; f < F1; ++f) acc += sp1[f] * l2w[f * F2 + tx];
        sp2[tx] = fmaxf(acc, 0.f); }
    __syncthreads();
    if (tx < F3) {
        float acc = l3b[tx];
        for (int f = 0; f < F2; ++f) acc += sp2[f] * l3w[f * F3 + tx];
        sp3[tx] = fmaxf(acc, 0.f); }
    __syncthreads();
    if (tx < 64) {
        float p = sp3[tx] * l4w[tx];
        for (int off = 32; off > 0; off >>= 1) p += __shfl_down(p, off, 64);
        if (tx == 0) outp[b] = p + l4b[0];
    }
}

// ---------------------------------------------------------------------------
// Workspace (<= 34,348,288 B, proven available).
#define OFF_M1    ((size_t)0)        // Mb1 bf16 34,816 B
#define OFF_M2    ((size_t)38400)    // Mb2 bf16 17,408 B
#define OFF_M3    ((size_t)57600)    // Mb3 bf16 17,408 B (ends 75,008)
#define OFF_AOFF  ((size_t)76800)
#define OFF_AEID  ((size_t)118016)
#define OFF_NRM   ((size_t)199936)
#define OFF_AA    ((size_t)281856)
#define OFF_HA    ((size_t)2891008)   // 4,000,000 -> 6,891,008
#define OFF_HB    ((size_t)6891008)   // 4,000,000 -> 10,891,008
#define OFF_MSG   ((size_t)10891008)  // 8,000,000 -> 18,891,008
#define OFF_SOFF  ((size_t)18891008)
#define OFF_DOFF  ((size_t)19291136)
#define OFF_DSLOT ((size_t)19691264)  // sdp: src-slot -> dst-pos
#define OFF_LOFF  ((size_t)20491264)
#define OFF_LNID  ((size_t)20532480)
#define OFF_CS    ((size_t)20932480)
#define OFF_CD    ((size_t)21332480)
#define OFF_CA    ((size_t)21732480)
#define OFF_CL    ((size_t)21773440)
#define OFF_US    ((size_t)21814400)
#define OFF_UD    ((size_t)22214400)
#define OFF_UA    ((size_t)22614400)
#define OFF_UL    ((size_t)22655360)
#define OFF_BSUM  ((size_t)22696320)
#define OFF_EAP   ((size_t)22697216)      // bf16x12 4,800,000 -> 27,497,216
#define OFF_SRCP  ((size_t)27497216)      // 800,000 -> 28,297,216
#define OFF_WP    ((size_t)28297216)      // 786,432 -> 29,083,648
#define OFF_SELFM ((size_t)29083648)      // bf16 4,000,000 -> 33,083,648
// ARMA overlays (NNConv buffers dead by then):
//   OB (odd-layer O): 2,891,008..10,755,328  (over hA/hB)
//   A0: 10,891,008 + 1,310,720 = 12,201,728  (over msg, dead after reduce2 #3)
//   OA (even-layer O): 18,619,648..26,483,968 (over msg tail + eaP)
#define OFF_OB    ((size_t)2891008)
#define OFF_A0    ((size_t)10891008)
#define OFF_OA    ((size_t)18619648)

extern "C" void kernel_launch(void* const* d_in, const int* in_sizes, int n_in,
                              void* d_out, int out_size, void* d_ws, size_t ws_size,
                              hipStream_t stream) {
    (void)in_sizes; (void)n_in; (void)out_size; (void)ws_size;
    const float* x   = (const float*)d_in[0];
    const int*   ei  = (const int*)d_in[1];
    const float* ea  = (const float*)d_in[2];
    const int*   lbl = (const int*)d_in[3];
    const float* af  = (const float*)d_in[4];
    const int*   aei = (const int*)d_in[5];
    const int*   bat = (const int*)d_in[6];
    const float* nn1w = (const float*)d_in[7];  const float* nn1b = (const float*)d_in[8];
    const float* rt1  = (const float*)d_in[9];  const float* b1   = (const float*)d_in[10];
    const float* nn2w = (const float*)d_in[11]; const float* nn2b = (const float*)d_in[12];
    const float* rt2  = (const float*)d_in[13]; const float* b2   = (const float*)d_in[14];
    const float* nn3w = (const float*)d_in[15]; const float* nn3b = (const float*)d_in[16];
    const float* rt3  = (const float*)d_in[17]; const float* b3   = (const float*)d_in[18];
    const float* ai   = (const float*)d_in[19]; const float* aw   = (const float*)d_in[20];
    const float* arw  = (const float*)d_in[21]; const float* abi  = (const float*)d_in[22];
    const float* l1w  = (const float*)d_in[23]; const float* l1b  = (const float*)d_in[24];
    const float* l2w  = (const float*)d_in[25]; const float* l2b  = (const float*)d_in[26];
    const float* l3w  = (const float*)d_in[27]; const float* l3b  = (const float*)d_in[28];
    const float* l4w  = (const float*)d_in[29]; const float* l4b  = (const float*)d_in[30];
    float* outp = (float*)d_out;

    char* ws = (char*)d_ws;
    u16*   Mb1   = (u16*)(ws + OFF_M1);
    u16*   Mb2   = (u16*)(ws + OFF_M2);
    u16*   Mb3   = (u16*)(ws + OFF_M3);
    int*   aoff  = (int*)(ws + OFF_AOFF);
    int*   aeid  = (int*)(ws + OFF_AEID);
    float* nrm   = (float*)(ws + OFF_NRM);
    float* aa    = (float*)(ws + OFF_AA);
    u16*   hA    = (u16*)(ws + OFF_HA);
    u16*   hB    = (u16*)(ws + OFF_HB);
    u16*   msg   = (u16*)(ws + OFF_MSG);
    int*   soff  = (int*)(ws + OFF_SOFF);
    int*   doff  = (int*)(ws + OFF_DOFF);
    int*   sdp   = (int*)(ws + OFF_DSLOT);
    int*   loff  = (int*)(ws + OFF_LOFF);
    int*   lnid  = (int*)(ws + OFF_LNID);
    int*   cs    = (int*)(ws + OFF_CS);
    int*   cd    = (int*)(ws + OFF_CD);
    int*   ca    = (int*)(ws + OFF_CA);
    int*   cl    = (int*)(ws + OFF_CL);
    int*   us    = (int*)(ws + OFF_US);
    int*   ud    = (int*)(ws + OFF_UD);
    int*   ua    = (int*)(ws + OFF_UA);
    int*   ul    = (int*)(ws + OFF_UL);
    int*   bsum  = (int*)(ws + OFF_BSUM);
    u16*   eaP   = (u16*)(ws + OFF_EAP);
    int*   srcP  = (int*)(ws + OFF_SRCP);
    u16*   Wp    = (u16*)(ws + OFF_WP);
    u16*   selfm = (u16*)(ws + OFF_SELFM);
    u16*   A0    = (u16*)(ws + OFF_A0);
    u16*   OA    = (u16*)(ws + OFF_OA);
    u16*   OB    = (u16*)(ws + OFF_OB);

    const int* esrc = ei;
    const int* edst = ei + E_ATOMS;
    const int* adst = aei + E_AMINO;

    // prep (merged prep + weight pack)
    k_prep<<<(PREP_N + 255) / 256, 256, 0, stream>>>(
        nn1w, nn1b, rt1, nn2w, nn2b, rt2, nn3w, nn3b, rt3,
        Mb1, Mb2, Mb3, af, aa, cs, cd, ca, cl, ai, aw, arw, Wp);
    k_csr_count<<<(2 * E_ATOMS + E_AMINO + N_ATOMS + 255) / 256, 256, 0, stream>>>(
        esrc, edst, adst, lbl, cs, cd, ca, cl);
    k_scan1<<<2 * NBS + 2 * NBA, 256, 0, stream>>>(cs, soff, cd, doff, ca, aoff, cl, loff, bsum);
    k_scan2<<<4, 128, 0, stream>>>(bsum, soff, doff, aoff, loff);
    k_scan3<<<2 * NBS + 2 * NBA, 256, 0, stream>>>(soff, doff, aoff, loff, bsum, us, ud, ua, ul);
    k_csr_fill<<<(E_ATOMS + 2 * E_AMINO + N_ATOMS + 255) / 256, 256, 0, stream>>>(
        esrc, edst, ea, us, srcP, eaP, ud, sdp, aei, ua, aeid, aoff, nrm, lbl, ul, lnid);

    // NNConv (edge v11 + separate streaming reduce)
    const int GT = N_ATOMS / NTILE;               // 6250
    const int GF = (N_ATOMS * HD + 255) / 256;    // 7813
    nnconv_edge11<DIN0, 2, true ><<<GT, 256, 0, stream>>>(x,  eaP, srcP, sdp, soff, Mb1, b1, msg, selfm);
    nnconv_reduce2<<<GF, 256, 0, stream>>>(selfm, doff, msg, hA);
    nnconv_edge11<HD,   1, false><<<GT, 256, 0, stream>>>(hA, eaP, srcP, sdp, soff, Mb2, b2, msg, selfm);
    nnconv_reduce2<<<GF, 256, 0, stream>>>(selfm, doff, msg, hB);
    nnconv_edge11<HD,   1, false><<<GT, 256, 0, stream>>>(hB, eaP, srcP, sdp, soff, Mb3, b3, msg, selfm);
    nnconv_reduce2<<<GF, 256, 0, stream>>>(selfm, doff, msg, hA);
    aa_gather<<<(N_AMINO * HD + 255) / 256, 256, 0, stream>>>(hA, loff, lnid, aa);

    // ARMA: gather/GEMM commuted; k_gaa + arma_l0 (R16 proven); lt 16-tiles (R22).
    const size_t KH = (size_t)N_AMINO * HA;
    k_gaa<<<(N_AMINO * 64 + 255) / 256, 256, 0, stream>>>(aa, aoff, aeid, aei, nrm, A0);
    arma_l0<<<dim3(160, KS), 256, 0, stream>>>(A0, Wp, abi, OA, KH);
    for (int t = 1; t < TL; ++t) {
        const u16* Oin  = (t & 1) ? OA : OB;
        u16*       Oout = (t & 1) ? OB : OA;
        arma_lt16<<<dim3(640, KS), 256, 0, stream>>>(
            Oin, Wp + WP0_ELEMS + (size_t)((t - 1) * KS) * 20480,
            abi + (size_t)t * KS * HA, aa, aoff, aeid, aei, nrm, Oout, KH);
    }
    // TL=7: final output (t=6, even) lands in OA.
    head2<<<NGRAPH, 256, 0, stream>>>(OA, KH, bat, l1w, l1b, l2w, l2b,
                                      l3w, l3b, l4w, l4b, outp);
}